// Round 1
// baseline (916.526 us; speedup 1.0000x reference)
//
#include <hip/hip_runtime.h>

// TransformerTGNN sequential scan, parallelized exactly via:
//   1) pointwise edge detection on raw up/u (up_hat>=.5 <=> up>=.5)
//   2) segmented max scan for up_max  -> up_hat
//   3) affine scan for alpha
//   4) affine scan for y (coeffs: end->(0,0), freeze->(1,0), else (1-alpha, alpha*up_hat))
//   5) "last setter value" scan for l_c, "last index" scans for start/true_start/label_frame
//   6) reduction over end events for loss/cnt
// Chunked: NC chunks, per-chunk sequential walk (exact within chunk), tiny serial
// middle scans over NC aggregates between phases.

#define NC   1024
#define MAXF 20

__global__ void k_events(const float* __restrict__ up, const float* __restrict__ u,
                         const float* __restrict__ lab, int ch,
                         int* hasC, int* lastC, float* sufMax,
                         int* lastU, int* lastL) {
    int ci = blockIdx.x * blockDim.x + threadIdx.x;
    if (ci >= NC) return;
    int base = ci * ch;
    float up_prev = base ? up[base - 1] : 0.f;
    float u_prev  = base ? u[base - 1]  : 0.f;
    int hC = 0, lC = -1, lU = -1, lL = -1;
    float m = 0.f;
    #pragma unroll 4
    for (int j = 0; j < ch; ++j) {
        int t = base + j;
        float upt = up[t], ut = u[t], labt = lab[t];
        bool cross = (up_prev < 0.5f) && (upt >= 0.5f);
        if (cross) { hC = 1; lC = t; m = upt; } else m = fmaxf(m, upt);
        if (u_prev == 0.f && ut == 1.f) lU = t;
        if (labt >= 0.5f && upt >= 0.5f) lL = t;
        up_prev = upt; u_prev = ut;
    }
    hasC[ci] = hC; lastC[ci] = lC; sufMax[ci] = m; lastU[ci] = lU; lastL[ci] = lL;
}

__global__ void k_scan_events(const int* hasC, const int* lastC, const float* sufMax,
                              const int* lastU, const int* lastL,
                              float* upmax_in, int* c_in, int* ts_in, int* lf_in) {
    float M = 0.f; int C = 0, TS = 0, LF = 0;
    for (int k = 0; k < NC; ++k) {
        upmax_in[k] = M; c_in[k] = C; ts_in[k] = TS; lf_in[k] = LF;
        if (hasC[k]) { C = lastC[k]; M = sufMax[k]; } else M = fmaxf(M, sufMax[k]);
        if (lastU[k] >= 0) TS = lastU[k];
        if (lastL[k] >= 0) LF = lastL[k];
    }
}

__global__ void k_uphat_alpha(const float* __restrict__ up, const float* __restrict__ a,
                              int ch, const float* upmax_in,
                              float* __restrict__ out_uphat, float* Ma, float* Ba) {
    int ci = blockIdx.x * blockDim.x + threadIdx.x;
    if (ci >= NC) return;
    int base = ci * ch;
    float up_prev = base ? up[base - 1] : 0.f;
    float m = upmax_in[ci];
    float MA = 1.f, BA = 0.f;   // alpha_out = MA*alpha_in + BA
    #pragma unroll 4
    for (int j = 0; j < ch; ++j) {
        int t = base + j;
        float upt = up[t];
        bool cross = (up_prev < 0.5f) && (upt >= 0.5f);
        m = cross ? upt : fmaxf(m, upt);
        float uph = (upt >= 0.5f) ? m : upt;
        out_uphat[t] = uph;
        float bt = (1.f - uph) * a[t];
        BA = uph * BA + bt;
        MA = uph * MA;
        up_prev = upt;
    }
    Ma[ci] = MA; Ba[ci] = BA;
}

__global__ void k_scan_affine(const float* M, const float* B, float* x_in) {
    float S = 0.f;
    for (int k = 0; k < NC; ++k) { x_in[k] = S; S = M[k] * S + B[k]; }
}

__global__ void k_alpha_y(const float* __restrict__ up, const float* __restrict__ a,
                          int ch, const float* __restrict__ out_uphat,
                          const float* alpha_in, const int* c_in,
                          float* __restrict__ out_alpha, float* My, float* By) {
    int ci = blockIdx.x * blockDim.x + threadIdx.x;
    if (ci >= NC) return;
    int base = ci * ch;
    float up_prev = base ? up[base - 1] : 0.f;
    float al = alpha_in[ci];
    int c = c_in[ci];
    float MY = 1.f, BY = 0.f;
    #pragma unroll 4
    for (int j = 0; j < ch; ++j) {
        int t = base + j;
        float upt = up[t];
        float uph = out_uphat[t];
        bool cross = (up_prev < 0.5f) && (upt >= 0.5f);
        if (cross) c = t;
        al = uph * al + (1.f - uph) * a[t];   // exact sequential recurrence in-chunk
        out_alpha[t] = al;
        bool end    = (up_prev >= 0.5f) && (upt < 0.5f);
        bool freeze = (upt >= 0.5f) && (c > 0) && (t - c > MAXF);
        float A, B;
        if (end)         { A = 0.f;       B = 0.f; }
        else if (freeze) { A = 1.f;       B = 0.f; }
        else             { A = 1.f - al;  B = al * uph; }
        BY = A * BY + B;
        MY = A * MY;
        up_prev = upt;
    }
    My[ci] = MY; By[ci] = BY;
}

__global__ void k_y_lc(const float* __restrict__ up, const float* __restrict__ lab,
                       int ch, const float* __restrict__ out_uphat,
                       const float* __restrict__ out_alpha,
                       const float* y_in, const int* c_in,
                       float* __restrict__ out_y, int* hasS, float* lastV) {
    int ci = blockIdx.x * blockDim.x + threadIdx.x;
    if (ci >= NC) return;
    int base = ci * ch;
    float up_prev = base ? up[base - 1] : 0.f;
    float y = y_in[ci];
    int c = c_in[ci];
    int hS = 0; float lV = 0.f;
    #pragma unroll 4
    for (int j = 0; j < ch; ++j) {
        int t = base + j;
        float upt = up[t];
        float uph = out_uphat[t];
        float al  = out_alpha[t];
        float labt = lab[t];
        bool cross = (up_prev < 0.5f) && (upt >= 0.5f);
        if (cross) c = t;
        bool end    = (up_prev >= 0.5f) && (upt < 0.5f);
        bool freeze = (upt >= 0.5f) && (c > 0) && (t - c > MAXF);
        float yr = al * uph + (1.f - al) * y;
        float yt = end ? 0.f : (freeze ? y : yr);
        out_y[t] = yt;
        // l_c post-state setters: end -> 0 (reset wins, it is applied last);
        // label event -> -1 (lab_lo) or (y - lab)^2 (lab_hi)
        if (end) { hS = 1; lV = 0.f; }
        else if (labt >= 0.5f) {
            hS = 1;
            lV = (upt < 0.5f) ? -1.f : (yt - labt) * (yt - labt);
        }
        y = yt; up_prev = upt;
    }
    hasS[ci] = hS; lastV[ci] = lV;
}

__global__ void k_scan_lc(const int* hasS, const float* lastV, float* lc_in) {
    float L = 0.f;
    for (int k = 0; k < NC; ++k) { lc_in[k] = L; if (hasS[k]) L = lastV[k]; }
}

__global__ void k_loss(const float* __restrict__ up, const float* __restrict__ u,
                       const float* __restrict__ lab, const float* __restrict__ th2,
                       int ch, const float* __restrict__ out_y,
                       const float* lc_in, const int* c_in, const int* ts_in, const int* lf_in,
                       float* lossP, float* cntP) {
    int ci = blockIdx.x * blockDim.x + threadIdx.x;
    if (ci >= NC) return;
    int base = ci * ch;
    float up_prev = base ? up[base - 1] : 0.f;
    float u_prev  = base ? u[base - 1]  : 0.f;
    float y_prev  = base ? out_y[base - 1] : 0.f;
    float lc = lc_in[ci];
    int c = c_in[ci], ts = ts_in[ci], lf = lf_in[ci];
    float loss = 0.f, cnt = 0.f;
    for (int j = 0; j < ch; ++j) {
        int t = base + j;
        float upt = up[t], ut = u[t], labt = lab[t];
        float yt = out_y[t];
        bool cross = (up_prev < 0.5f) && (upt >= 0.5f);
        if (cross) c = t;
        if (u_prev == 0.f && ut == 1.f) ts = t;          // true_start update (step 1)
        bool islab = labt >= 0.5f;
        if (islab && upt >= 0.5f) lf = t;                // label_frame (lab_hi)
        float lc_used = lc;
        if (islab) lc_used = (upt < 0.5f) ? -1.f : (yt - labt) * (yt - labt);
        bool end = (up_prev >= 0.5f) && (upt < 0.5f);
        if (end) {
            int dur = lf - ts + 1;
            bool good = (dur >= 3) && (dur <= 40);
            if ((lc_used != -1.f) && (lc_used != 0.f) && good) { loss += lc_used; cnt += 1.f; }
            if ((lc_used == 0.f) && (y_prev >= 0.5f)) {
                int d = t - c;
                int idx = (d < MAXF) ? d : (MAXF - 1);
                if (idx < 0) idx = 0; if (idx > MAXF - 1) idx = MAXF - 1;
                float diff = y_prev - th2[idx];
                loss += diff * diff; cnt += 1.f;
            }
            lc = 0.f;
        } else if (islab) {
            lc = lc_used;
        }
        y_prev = yt; up_prev = upt; u_prev = ut;
    }
    lossP[ci] = loss; cntP[ci] = cnt;
}

__global__ void k_reduce(const float* lossP, const float* cntP, float* out, int T) {
    float L = 0.f, C = 0.f;
    for (int k = 0; k < NC; ++k) { L += lossP[k]; C += cntP[k]; }
    out[3 * T]     = L;
    out[3 * T + 1] = C;
}

extern "C" void kernel_launch(void* const* d_in, const int* in_sizes, int n_in,
                              void* d_out, int out_size, void* d_ws, size_t ws_size,
                              hipStream_t stream) {
    const float* a   = (const float*)d_in[0];
    const float* u   = (const float*)d_in[1];
    const float* up  = (const float*)d_in[2];
    const float* lab = (const float*)d_in[3];
    const float* th2 = (const float*)d_in[4];
    float* out = (float*)d_out;
    const int T  = in_sizes[0];
    const int ch = T / NC;

    float* W  = (float*)d_ws;
    int*   Wi = (int*)d_ws;
    int*   hasC     = Wi + 0 * NC;
    int*   lastC    = Wi + 1 * NC;
    float* sufMax   = W  + 2 * NC;
    int*   lastU    = Wi + 3 * NC;
    int*   lastL    = Wi + 4 * NC;
    float* upmax_in = W  + 5 * NC;
    int*   c_in     = Wi + 6 * NC;
    int*   ts_in    = Wi + 7 * NC;
    int*   lf_in    = Wi + 8 * NC;
    float* Ma       = W  + 9 * NC;
    float* Ba       = W  + 10 * NC;
    float* alpha_in = W  + 11 * NC;
    float* My       = W  + 12 * NC;
    float* By       = W  + 13 * NC;
    float* y_in     = W  + 14 * NC;
    int*   hasS     = Wi + 15 * NC;
    float* lastV    = W  + 16 * NC;
    float* lc_in    = W  + 17 * NC;
    float* lossP    = W  + 18 * NC;
    float* cntP     = W  + 19 * NC;

    float* out_y     = out;
    float* out_alpha = out + T;
    float* out_uphat = out + 2 * T;

    dim3 g(NC / 64), b(64);
    k_events<<<g, b, 0, stream>>>(up, u, lab, ch, hasC, lastC, sufMax, lastU, lastL);
    k_scan_events<<<1, 1, 0, stream>>>(hasC, lastC, sufMax, lastU, lastL,
                                       upmax_in, c_in, ts_in, lf_in);
    k_uphat_alpha<<<g, b, 0, stream>>>(up, a, ch, upmax_in, out_uphat, Ma, Ba);
    k_scan_affine<<<1, 1, 0, stream>>>(Ma, Ba, alpha_in);
    k_alpha_y<<<g, b, 0, stream>>>(up, a, ch, out_uphat, alpha_in, c_in, out_alpha, My, By);
    k_scan_affine<<<1, 1, 0, stream>>>(My, By, y_in);
    k_y_lc<<<g, b, 0, stream>>>(up, lab, ch, out_uphat, out_alpha, y_in, c_in,
                                out_y, hasS, lastV);
    k_scan_lc<<<1, 1, 0, stream>>>(hasS, lastV, lc_in);
    k_loss<<<g, b, 0, stream>>>(up, u, lab, th2, ch, out_y, lc_in, c_in, ts_in, lf_in,
                                lossP, cntP);
    k_reduce<<<1, 1, 0, stream>>>(lossP, cntP, out, T);
}

// Round 2
// 140.764 us; speedup vs baseline: 6.5111x; 6.5111x over previous
//
#include <hip/hip_runtime.h>

// TransformerTGNN sequential scan, parallelized exactly via:
//   1) pointwise edge detection on raw up/u (up_hat>=.5 <=> up>=.5)
//   2) segmented max scan for up_max  -> up_hat
//   3) affine scan for alpha
//   4) affine scan for y (coeffs: end->(0,0), freeze->(1,0), else (1-alpha, alpha*up_hat))
//   5) "last setter value" scan for l_c, "last index" scans for start/true_start/label_frame
//   6) reduction over end events for loss/cnt
// R1: middle scans are now single-block 256-thread LDS parallel scans (were
// single-thread serial loops at ~267us each); NC raised 1024->4096.

#define NC   4096
#define SCT  256            // scan block threads
#define ITS  (NC / SCT)     // items per scan thread
#define MAXF 20

__global__ void k_events(const float* __restrict__ up, const float* __restrict__ u,
                         const float* __restrict__ lab, int ch,
                         int* hasC, int* lastC, float* sufMax,
                         int* lastU, int* lastL) {
    int ci = blockIdx.x * blockDim.x + threadIdx.x;
    if (ci >= NC) return;
    int base = ci * ch;
    float up_prev = base ? up[base - 1] : 0.f;
    float u_prev  = base ? u[base - 1]  : 0.f;
    int hC = 0, lC = -1, lU = -1, lL = -1;
    float m = 0.f;
    #pragma unroll 4
    for (int j = 0; j < ch; ++j) {
        int t = base + j;
        float upt = up[t], ut = u[t], labt = lab[t];
        bool cross = (up_prev < 0.5f) && (upt >= 0.5f);
        if (cross) { hC = 1; lC = t; m = upt; } else m = fmaxf(m, upt);
        if (u_prev == 0.f && ut == 1.f) lU = t;
        if (labt >= 0.5f && upt >= 0.5f) lL = t;
        up_prev = upt; u_prev = ut;
    }
    hasC[ci] = hC; lastC[ci] = lC; sufMax[ci] = m; lastU[ci] = lU; lastL[ci] = lL;
}

// parallel scan over segmented-max / last-index monoids
__global__ void k_scan_events(const int* hasC, const int* lastC, const float* sufMax,
                              const int* lastU, const int* lastL,
                              float* upmax_in, int* c_in, int* ts_in, int* lf_in) {
    const int tid = threadIdx.x;
    const int base = tid * ITS;
    int ah = 0; float am = 0.f; int ac = 0, au = -1, al = -1;
    for (int q = 0; q < ITS; ++q) {
        int k = base + q;
        int h = hasC[k]; float m = sufMax[k];
        if (h) { ah = 1; am = m; ac = lastC[k]; } else am = fmaxf(am, m);
        int lu = lastU[k], ll = lastL[k];
        if (lu >= 0) au = lu;
        if (ll >= 0) al = ll;
    }
    __shared__ int sH[SCT]; __shared__ float sM[SCT];
    __shared__ int sC[SCT], sU[SCT], sL[SCT];
    sH[tid] = ah; sM[tid] = am; sC[tid] = ac; sU[tid] = au; sL[tid] = al;
    __syncthreads();
    int mh = ah; float mm = am; int mc = ac, mu = au, ml = al;
    for (int off = 1; off < SCT; off <<= 1) {
        int ph = 0; float pm = 0.f; int pc = 0, pu = -1, pl = -1;
        if (tid >= off) { ph = sH[tid-off]; pm = sM[tid-off]; pc = sC[tid-off];
                          pu = sU[tid-off]; pl = sL[tid-off]; }
        __syncthreads();
        if (tid >= off) {
            if (!mh) { mm = fmaxf(pm, mm); mc = pc; mh = ph; }
            if (mu < 0) mu = pu;
            if (ml < 0) ml = pl;
            sH[tid] = mh; sM[tid] = mm; sC[tid] = mc; sU[tid] = mu; sL[tid] = ml;
        }
        __syncthreads();
    }
    int eh = 0; float em = 0.f; int ec = 0, eu = -1, el = -1;
    if (tid > 0) { eh = sH[tid-1]; em = sM[tid-1]; ec = sC[tid-1];
                   eu = sU[tid-1]; el = sL[tid-1]; }
    for (int q = 0; q < ITS; ++q) {
        int k = base + q;
        upmax_in[k] = em; c_in[k] = ec;
        ts_in[k] = (eu >= 0) ? eu : 0;
        lf_in[k] = (el >= 0) ? el : 0;
        int h = hasC[k]; float m = sufMax[k];
        if (h) { eh = 1; em = m; ec = lastC[k]; } else em = fmaxf(em, m);
        int lu = lastU[k], ll = lastL[k];
        if (lu >= 0) eu = lu;
        if (ll >= 0) el = ll;
    }
}

__global__ void k_uphat_alpha(const float* __restrict__ up, const float* __restrict__ a,
                              int ch, const float* upmax_in,
                              float* __restrict__ out_uphat, float* Ma, float* Ba) {
    int ci = blockIdx.x * blockDim.x + threadIdx.x;
    if (ci >= NC) return;
    int base = ci * ch;
    float up_prev = base ? up[base - 1] : 0.f;
    float m = upmax_in[ci];
    float MA = 1.f, BA = 0.f;   // alpha_out = MA*alpha_in + BA
    #pragma unroll 4
    for (int j = 0; j < ch; ++j) {
        int t = base + j;
        float upt = up[t];
        bool cross = (up_prev < 0.5f) && (upt >= 0.5f);
        m = cross ? upt : fmaxf(m, upt);
        float uph = (upt >= 0.5f) ? m : upt;
        out_uphat[t] = uph;
        float bt = (1.f - uph) * a[t];
        BA = uph * BA + bt;
        MA = uph * MA;
        up_prev = upt;
    }
    Ma[ci] = MA; Ba[ci] = BA;
}

// parallel affine-composition scan: x_in[k] = (T_{k-1} o ... o T_0)(0)
__global__ void k_scan_affine(const float* M, const float* B, float* x_in) {
    const int tid = threadIdx.x;
    const int base = tid * ITS;
    float aM = 1.f, aB = 0.f;
    for (int q = 0; q < ITS; ++q) {
        int k = base + q;
        float m = M[k], b = B[k];
        aB = m * aB + b; aM = m * aM;
    }
    __shared__ float sM[SCT], sB[SCT];
    sM[tid] = aM; sB[tid] = aB;
    __syncthreads();
    float mM = aM, mB = aB;
    for (int off = 1; off < SCT; off <<= 1) {
        float pM = 1.f, pB = 0.f;
        if (tid >= off) { pM = sM[tid-off]; pB = sB[tid-off]; }
        __syncthreads();
        if (tid >= off) { mB = mM * pB + mB; mM = mM * pM; sM[tid] = mM; sB[tid] = mB; }
        __syncthreads();
    }
    float x = (tid > 0) ? sB[tid-1] : 0.f;
    for (int q = 0; q < ITS; ++q) {
        int k = base + q;
        x_in[k] = x;
        x = M[k] * x + B[k];
    }
}

__global__ void k_alpha_y(const float* __restrict__ up, const float* __restrict__ a,
                          int ch, const float* __restrict__ out_uphat,
                          const float* alpha_in, const int* c_in,
                          float* __restrict__ out_alpha, float* My, float* By) {
    int ci = blockIdx.x * blockDim.x + threadIdx.x;
    if (ci >= NC) return;
    int base = ci * ch;
    float up_prev = base ? up[base - 1] : 0.f;
    float al = alpha_in[ci];
    int c = c_in[ci];
    float MY = 1.f, BY = 0.f;
    #pragma unroll 4
    for (int j = 0; j < ch; ++j) {
        int t = base + j;
        float upt = up[t];
        float uph = out_uphat[t];
        bool cross = (up_prev < 0.5f) && (upt >= 0.5f);
        if (cross) c = t;
        al = uph * al + (1.f - uph) * a[t];
        out_alpha[t] = al;
        bool end    = (up_prev >= 0.5f) && (upt < 0.5f);
        bool freeze = (upt >= 0.5f) && (c > 0) && (t - c > MAXF);
        float A, B;
        if (end)         { A = 0.f;       B = 0.f; }
        else if (freeze) { A = 1.f;       B = 0.f; }
        else             { A = 1.f - al;  B = al * uph; }
        BY = A * BY + B;
        MY = A * MY;
        up_prev = upt;
    }
    My[ci] = MY; By[ci] = BY;
}

__global__ void k_y_lc(const float* __restrict__ up, const float* __restrict__ lab,
                       int ch, const float* __restrict__ out_uphat,
                       const float* __restrict__ out_alpha,
                       const float* y_in, const int* c_in,
                       float* __restrict__ out_y, int* hasS, float* lastV) {
    int ci = blockIdx.x * blockDim.x + threadIdx.x;
    if (ci >= NC) return;
    int base = ci * ch;
    float up_prev = base ? up[base - 1] : 0.f;
    float y = y_in[ci];
    int c = c_in[ci];
    int hS = 0; float lV = 0.f;
    #pragma unroll 4
    for (int j = 0; j < ch; ++j) {
        int t = base + j;
        float upt = up[t];
        float uph = out_uphat[t];
        float al  = out_alpha[t];
        float labt = lab[t];
        bool cross = (up_prev < 0.5f) && (upt >= 0.5f);
        if (cross) c = t;
        bool end    = (up_prev >= 0.5f) && (upt < 0.5f);
        bool freeze = (upt >= 0.5f) && (c > 0) && (t - c > MAXF);
        float yr = al * uph + (1.f - al) * y;
        float yt = end ? 0.f : (freeze ? y : yr);
        out_y[t] = yt;
        if (end) { hS = 1; lV = 0.f; }
        else if (labt >= 0.5f) {
            hS = 1;
            lV = (upt < 0.5f) ? -1.f : (yt - labt) * (yt - labt);
        }
        y = yt; up_prev = upt;
    }
    hasS[ci] = hS; lastV[ci] = lV;
}

// parallel "last setter" scan
__global__ void k_scan_lc(const int* hasS, const float* lastV, float* lc_in) {
    const int tid = threadIdx.x;
    const int base = tid * ITS;
    int ah = 0; float av = 0.f;
    for (int q = 0; q < ITS; ++q) {
        int k = base + q;
        if (hasS[k]) { ah = 1; av = lastV[k]; }
    }
    __shared__ int sH[SCT]; __shared__ float sV[SCT];
    sH[tid] = ah; sV[tid] = av;
    __syncthreads();
    int mh = ah; float mv = av;
    for (int off = 1; off < SCT; off <<= 1) {
        int ph = 0; float pv = 0.f;
        if (tid >= off) { ph = sH[tid-off]; pv = sV[tid-off]; }
        __syncthreads();
        if (tid >= off) { if (!mh) { mh = ph; mv = pv; } sH[tid] = mh; sV[tid] = mv; }
        __syncthreads();
    }
    float L = 0.f;
    if (tid > 0 && sH[tid-1]) L = sV[tid-1];
    for (int q = 0; q < ITS; ++q) {
        int k = base + q;
        lc_in[k] = L;
        if (hasS[k]) L = lastV[k];
    }
}

__global__ void k_loss(const float* __restrict__ up, const float* __restrict__ u,
                       const float* __restrict__ lab, const float* __restrict__ th2,
                       int ch, const float* __restrict__ out_y,
                       const float* lc_in, const int* c_in, const int* ts_in, const int* lf_in,
                       float* lossP, float* cntP) {
    int ci = blockIdx.x * blockDim.x + threadIdx.x;
    if (ci >= NC) return;
    int base = ci * ch;
    float up_prev = base ? up[base - 1] : 0.f;
    float u_prev  = base ? u[base - 1]  : 0.f;
    float y_prev  = base ? out_y[base - 1] : 0.f;
    float lc = lc_in[ci];
    int c = c_in[ci], ts = ts_in[ci], lf = lf_in[ci];
    float loss = 0.f, cnt = 0.f;
    for (int j = 0; j < ch; ++j) {
        int t = base + j;
        float upt = up[t], ut = u[t], labt = lab[t];
        float yt = out_y[t];
        bool cross = (up_prev < 0.5f) && (upt >= 0.5f);
        if (cross) c = t;
        if (u_prev == 0.f && ut == 1.f) ts = t;
        bool islab = labt >= 0.5f;
        if (islab && upt >= 0.5f) lf = t;
        float lc_used = lc;
        if (islab) lc_used = (upt < 0.5f) ? -1.f : (yt - labt) * (yt - labt);
        bool end = (up_prev >= 0.5f) && (upt < 0.5f);
        if (end) {
            int dur = lf - ts + 1;
            bool good = (dur >= 3) && (dur <= 40);
            if ((lc_used != -1.f) && (lc_used != 0.f) && good) { loss += lc_used; cnt += 1.f; }
            if ((lc_used == 0.f) && (y_prev >= 0.5f)) {
                int d = t - c;
                int idx = (d < MAXF) ? d : (MAXF - 1);
                if (idx < 0) idx = 0; if (idx > MAXF - 1) idx = MAXF - 1;
                float diff = y_prev - th2[idx];
                loss += diff * diff; cnt += 1.f;
            }
            lc = 0.f;
        } else if (islab) {
            lc = lc_used;
        }
        y_prev = yt; up_prev = upt; u_prev = ut;
    }
    lossP[ci] = loss; cntP[ci] = cnt;
}

__global__ void k_reduce(const float* lossP, const float* cntP, float* out, int T) {
    const int tid = threadIdx.x;
    float L = 0.f, C = 0.f;
    for (int q = 0; q < ITS; ++q) {
        int k = tid * ITS + q;
        L += lossP[k]; C += cntP[k];
    }
    __shared__ float sL[SCT], sC[SCT];
    sL[tid] = L; sC[tid] = C;
    __syncthreads();
    for (int off = SCT / 2; off > 0; off >>= 1) {
        if (tid < off) { sL[tid] += sL[tid + off]; sC[tid] += sC[tid + off]; }
        __syncthreads();
    }
    if (tid == 0) { out[3 * T] = sL[0]; out[3 * T + 1] = sC[0]; }
}

extern "C" void kernel_launch(void* const* d_in, const int* in_sizes, int n_in,
                              void* d_out, int out_size, void* d_ws, size_t ws_size,
                              hipStream_t stream) {
    const float* a   = (const float*)d_in[0];
    const float* u   = (const float*)d_in[1];
    const float* up  = (const float*)d_in[2];
    const float* lab = (const float*)d_in[3];
    const float* th2 = (const float*)d_in[4];
    float* out = (float*)d_out;
    const int T  = in_sizes[0];
    const int ch = T / NC;

    float* W  = (float*)d_ws;
    int*   Wi = (int*)d_ws;
    int*   hasC     = Wi + 0 * NC;
    int*   lastC    = Wi + 1 * NC;
    float* sufMax   = W  + 2 * NC;
    int*   lastU    = Wi + 3 * NC;
    int*   lastL    = Wi + 4 * NC;
    float* upmax_in = W  + 5 * NC;
    int*   c_in     = Wi + 6 * NC;
    int*   ts_in    = Wi + 7 * NC;
    int*   lf_in    = Wi + 8 * NC;
    float* Ma       = W  + 9 * NC;
    float* Ba       = W  + 10 * NC;
    float* alpha_in = W  + 11 * NC;
    float* My       = W  + 12 * NC;
    float* By       = W  + 13 * NC;
    float* y_in     = W  + 14 * NC;
    int*   hasS     = Wi + 15 * NC;
    float* lastV    = W  + 16 * NC;
    float* lc_in    = W  + 17 * NC;
    float* lossP    = W  + 18 * NC;
    float* cntP     = W  + 19 * NC;

    float* out_y     = out;
    float* out_alpha = out + T;
    float* out_uphat = out + 2 * T;

    dim3 g(NC / 64), b(64);
    k_events<<<g, b, 0, stream>>>(up, u, lab, ch, hasC, lastC, sufMax, lastU, lastL);
    k_scan_events<<<1, SCT, 0, stream>>>(hasC, lastC, sufMax, lastU, lastL,
                                         upmax_in, c_in, ts_in, lf_in);
    k_uphat_alpha<<<g, b, 0, stream>>>(up, a, ch, upmax_in, out_uphat, Ma, Ba);
    k_scan_affine<<<1, SCT, 0, stream>>>(Ma, Ba, alpha_in);
    k_alpha_y<<<g, b, 0, stream>>>(up, a, ch, out_uphat, alpha_in, c_in, out_alpha, My, By);
    k_scan_affine<<<1, SCT, 0, stream>>>(My, By, y_in);
    k_y_lc<<<g, b, 0, stream>>>(up, lab, ch, out_uphat, out_alpha, y_in, c_in,
                                out_y, hasS, lastV);
    k_scan_lc<<<1, SCT, 0, stream>>>(hasS, lastV, lc_in);
    k_loss<<<g, b, 0, stream>>>(up, u, lab, th2, ch, out_y, lc_in, c_in, ts_in, lf_in,
                                lossP, cntP);
    k_reduce<<<1, 1 * SCT, 0, stream>>>(lossP, cntP, out, T);
}

// Round 3
// 121.510 us; speedup vs baseline: 7.5428x; 1.1585x over previous
//
#include <hip/hip_runtime.h>

// TransformerTGNN scan — single fused persistent kernel.
// 128 blocks x 256 threads (<=256 CUs -> all co-resident), chunk = 8 elems/thread.
// Phases separated by device-scope atomic grid barriers (counters zeroed by a
// memset node each launch -> graph-replay safe, deterministic):
//   W1: load inputs to regs (float4), events monoid (seg-max/last-idx) thread agg
//       + block scan.                                      [GB0]
//   R1: every block redundantly scans 128 block aggs -> per-thread m/c/ts/lf.
//   W2: up_hat (written), alpha affine agg + block scan.   [GB1]
//   R2: global affine scan -> alpha_in.
//   W3: alpha (written), y affine agg + block scan.        [GB2]
//   R3: global affine scan -> y_in.
//   W4: y (written), loss for lc-known ends, <=1 pending lc-dependent end per
//       thread (any end is an lc-setter), lc setter agg + block scan. [GB3]
//   R4: global lc scan -> lc_in; W5: resolve pendings, block reduce.  [GB4]
//   block0: reduce 128 partials -> out[3T], out[3T+1].

#define THREADS 256
#define NBLK    128
#define CH      8
#define MAXF    20

__device__ __forceinline__ void gb_wait(unsigned* c) {
    __threadfence();
    __syncthreads();
    if (threadIdx.x == 0) {
        __hip_atomic_fetch_add(c, 1u, __ATOMIC_ACQ_REL, __HIP_MEMORY_SCOPE_AGENT);
        while (__hip_atomic_load(c, __ATOMIC_ACQUIRE, __HIP_MEMORY_SCOPE_AGENT) < NBLK)
            __builtin_amdgcn_s_sleep(1);
    }
    __syncthreads();
    __threadfence();
}

__global__ void __launch_bounds__(THREADS, 1)
tg_fused(const float* __restrict__ ga, const float* __restrict__ gu,
         const float* __restrict__ gup, const float* __restrict__ glab,
         const float* __restrict__ gth2, float* __restrict__ out, int T,
         unsigned* __restrict__ ctr, float* __restrict__ W)
{
    int*   evH  = (int*)(W + 0 * NBLK);
    float* evM  =        W + 1 * NBLK;
    int*   evC  = (int*)(W + 2 * NBLK);
    int*   evU  = (int*)(W + 3 * NBLK);
    int*   evL  = (int*)(W + 4 * NBLK);
    float* aMg  =        W + 5 * NBLK;
    float* aBg  =        W + 6 * NBLK;
    float* yMg  =        W + 7 * NBLK;
    float* yBg  =        W + 8 * NBLK;
    int*   lcHg = (int*)(W + 9 * NBLK);
    float* lcVg =        W + 10 * NBLK;
    float* lossB =       W + 11 * NBLK;
    float* cntB  =       W + 12 * NBLK;

    const int tid = threadIdx.x, b = blockIdx.x;
    const int p = b * THREADS + tid;
    const int base = p * CH;

    __shared__ float sf0[THREADS], sf1[THREADS];
    __shared__ int si0[THREADS], si1[THREADS], si2[THREADS], si3[THREADS];
    __shared__ float sth2[MAXF];
    if (tid < MAXF) sth2[tid] = gth2[tid];

    // ---------------- W1: load inputs ----------------
    float upv[CH], uv[CH], labv[CH], av[CH];
    {
        float4 t0 = *(const float4*)(gup + base);
        float4 t1 = *(const float4*)(gup + base + 4);
        upv[0]=t0.x; upv[1]=t0.y; upv[2]=t0.z; upv[3]=t0.w;
        upv[4]=t1.x; upv[5]=t1.y; upv[6]=t1.z; upv[7]=t1.w;
        t0 = *(const float4*)(gu + base);  t1 = *(const float4*)(gu + base + 4);
        uv[0]=t0.x; uv[1]=t0.y; uv[2]=t0.z; uv[3]=t0.w;
        uv[4]=t1.x; uv[5]=t1.y; uv[6]=t1.z; uv[7]=t1.w;
        t0 = *(const float4*)(glab + base); t1 = *(const float4*)(glab + base + 4);
        labv[0]=t0.x; labv[1]=t0.y; labv[2]=t0.z; labv[3]=t0.w;
        labv[4]=t1.x; labv[5]=t1.y; labv[6]=t1.z; labv[7]=t1.w;
        t0 = *(const float4*)(ga + base);  t1 = *(const float4*)(ga + base + 4);
        av[0]=t0.x; av[1]=t0.y; av[2]=t0.z; av[3]=t0.w;
        av[4]=t1.x; av[5]=t1.y; av[6]=t1.z; av[7]=t1.w;
    }
    const float up_prev0 = base ? gup[base - 1] : 0.f;
    const float u_prev0  = base ? gu[base - 1]  : 0.f;

    // events thread aggregate
    int th = 0, tc = 0, tlu = -1, tll = -1; float tm = 0.f;
    {
        float pu = up_prev0, puu = u_prev0;
        #pragma unroll
        for (int j = 0; j < CH; ++j) {
            float x = upv[j];
            bool cross = (pu < 0.5f) && (x >= 0.5f);
            if (cross) { th = 1; tc = base + j; tm = x; } else tm = fmaxf(tm, x);
            if (puu == 0.f && uv[j] == 1.f) tlu = base + j;
            if (labv[j] >= 0.5f && x >= 0.5f) tll = base + j;
            pu = x; puu = uv[j];
        }
    }
    // block inclusive scan (events monoid)
    si0[tid] = th; sf0[tid] = tm; si1[tid] = tc; si2[tid] = tlu; si3[tid] = tll;
    __syncthreads();
    {
        int mh = th; float mm = tm; int mc = tc, mu = tlu, ml = tll;
        for (int off = 1; off < THREADS; off <<= 1) {
            int ph = 0; float pm = 0.f; int pc = 0, pqu = -1, pql = -1;
            if (tid >= off) { ph = si0[tid-off]; pm = sf0[tid-off]; pc = si1[tid-off];
                              pqu = si2[tid-off]; pql = si3[tid-off]; }
            __syncthreads();
            if (tid >= off) {
                if (!mh) { mm = fmaxf(pm, mm); mc = pc; mh = ph; }
                if (mu < 0) mu = pqu;
                if (ml < 0) ml = pql;
                si0[tid] = mh; sf0[tid] = mm; si1[tid] = mc; si2[tid] = mu; si3[tid] = ml;
            }
            __syncthreads();
        }
    }
    const int   xh  = tid ? si0[tid-1] : 0;
    const float xm  = tid ? sf0[tid-1] : 0.f;
    const int   xc  = tid ? si1[tid-1] : 0;
    const int   xlu = tid ? si2[tid-1] : -1;
    const int   xll = tid ? si3[tid-1] : -1;
    if (tid == THREADS-1) { evH[b]=si0[tid]; evM[b]=sf0[tid]; evC[b]=si1[tid];
                            evU[b]=si2[tid]; evL[b]=si3[tid]; }
    gb_wait(ctr + 0);

    // ---------------- R1: redundant global events scan ----------------
    if (tid < NBLK) { si0[tid]=evH[tid]; sf0[tid]=evM[tid]; si1[tid]=evC[tid];
                      si2[tid]=evU[tid]; si3[tid]=evL[tid]; }
    __syncthreads();
    for (int off = 1; off < NBLK; off <<= 1) {
        int ph=0, pc=0, pqu=-1, pql=-1; float pm=0.f; int act = (tid < NBLK) && (tid >= off);
        int mh=0, mc=0, mu=-1, ml=-1; float mm=0.f;
        if (act) { ph=si0[tid-off]; pm=sf0[tid-off]; pc=si1[tid-off]; pqu=si2[tid-off]; pql=si3[tid-off];
                   mh=si0[tid]; mm=sf0[tid]; mc=si1[tid]; mu=si2[tid]; ml=si3[tid]; }
        __syncthreads();
        if (act) {
            if (!mh) { mm = fmaxf(pm, mm); mc = pc; mh = ph; }
            if (mu < 0) mu = pqu;
            if (ml < 0) ml = pql;
            si0[tid]=mh; sf0[tid]=mm; si1[tid]=mc; si2[tid]=mu; si3[tid]=ml;
        }
        __syncthreads();
    }
    float blk_m = 0.f; int blk_c = 0, blk_ts = 0, blk_lf = 0;
    if (b > 0) {
        int gh = si0[b-1]; float gm = sf0[b-1]; int gc = si1[b-1], gqu = si2[b-1], gql = si3[b-1];
        blk_m = gm; blk_c = gh ? gc : 0;
        blk_ts = (gqu >= 0) ? gqu : 0; blk_lf = (gql >= 0) ? gql : 0;
    }
    const float m_in  = xh ? xm : fmaxf(blk_m, xm);
    const int   c_in  = xh ? xc : blk_c;
    const int   ts_in = (xlu >= 0) ? xlu : blk_ts;
    const int   lf_in = (xll >= 0) ? xll : blk_lf;

    // ---------------- W2: up_hat + alpha affine agg ----------------
    float uphv[CH];
    float MA = 1.f, BA = 0.f;
    {
        float m = m_in; float pu = up_prev0;
        #pragma unroll
        for (int j = 0; j < CH; ++j) {
            float x = upv[j];
            bool cross = (pu < 0.5f) && (x >= 0.5f);
            m = cross ? x : fmaxf(m, x);
            float uph = (x >= 0.5f) ? m : x;
            uphv[j] = uph;
            BA = uph * BA + (1.f - uph) * av[j];
            MA = uph * MA;
            pu = x;
        }
        *(float4*)(out + 2*T + base)     = make_float4(uphv[0],uphv[1],uphv[2],uphv[3]);
        *(float4*)(out + 2*T + base + 4) = make_float4(uphv[4],uphv[5],uphv[6],uphv[7]);
    }
    __syncthreads();
    sf0[tid] = MA; sf1[tid] = BA;
    __syncthreads();
    {
        float mM = MA, mB = BA;
        for (int off = 1; off < THREADS; off <<= 1) {
            float pM = 1.f, pB = 0.f;
            if (tid >= off) { pM = sf0[tid-off]; pB = sf1[tid-off]; }
            __syncthreads();
            if (tid >= off) { mB = mM * pB + mB; mM = mM * pM; sf0[tid] = mM; sf1[tid] = mB; }
            __syncthreads();
        }
    }
    const float txM = tid ? sf0[tid-1] : 1.f;
    const float txB = tid ? sf1[tid-1] : 0.f;
    if (tid == THREADS-1) { aMg[b] = sf0[tid]; aBg[b] = sf1[tid]; }
    gb_wait(ctr + 1);

    // ---------------- R2: global alpha affine scan ----------------
    if (tid < NBLK) { sf0[tid] = aMg[tid]; sf1[tid] = aBg[tid]; }
    __syncthreads();
    for (int off = 1; off < NBLK; off <<= 1) {
        int act = (tid < NBLK) && (tid >= off);
        float pM = 1.f, pB = 0.f, mM = 1.f, mB = 0.f;
        if (act) { pM = sf0[tid-off]; pB = sf1[tid-off]; mM = sf0[tid]; mB = sf1[tid]; }
        __syncthreads();
        if (act) { mB = mM * pB + mB; mM = mM * pM; sf0[tid] = mM; sf1[tid] = mB; }
        __syncthreads();
    }
    const float a_blk = (b > 0) ? sf1[b-1] : 0.f;
    const float alpha_in = txM * a_blk + txB;

    // ---------------- W3: alpha + y affine agg ----------------
    float alv[CH];
    float MY = 1.f, BY = 0.f;
    {
        float al = alpha_in; int c = c_in; float pu = up_prev0;
        #pragma unroll
        for (int j = 0; j < CH; ++j) {
            int t = base + j;
            float x = upv[j];
            bool cross = (pu < 0.5f) && (x >= 0.5f);
            if (cross) c = t;
            float uph = uphv[j];
            al = uph * al + (1.f - uph) * av[j];
            alv[j] = al;
            bool end    = (pu >= 0.5f) && (x < 0.5f);
            bool freeze = (x >= 0.5f) && (c > 0) && ((t - c) > MAXF);
            float A, B;
            if (end)         { A = 0.f;      B = 0.f; }
            else if (freeze) { A = 1.f;      B = 0.f; }
            else             { A = 1.f - al; B = al * uph; }
            BY = A * BY + B;
            MY = A * MY;
            pu = x;
        }
        *(float4*)(out + T + base)     = make_float4(alv[0],alv[1],alv[2],alv[3]);
        *(float4*)(out + T + base + 4) = make_float4(alv[4],alv[5],alv[6],alv[7]);
    }
    __syncthreads();
    sf0[tid] = MY; sf1[tid] = BY;
    __syncthreads();
    {
        float mM = MY, mB = BY;
        for (int off = 1; off < THREADS; off <<= 1) {
            float pM = 1.f, pB = 0.f;
            if (tid >= off) { pM = sf0[tid-off]; pB = sf1[tid-off]; }
            __syncthreads();
            if (tid >= off) { mB = mM * pB + mB; mM = mM * pM; sf0[tid] = mM; sf1[tid] = mB; }
            __syncthreads();
        }
    }
    const float tyM = tid ? sf0[tid-1] : 1.f;
    const float tyB = tid ? sf1[tid-1] : 0.f;
    if (tid == THREADS-1) { yMg[b] = sf0[tid]; yBg[b] = sf1[tid]; }
    gb_wait(ctr + 2);

    // ---------------- R3: global y affine scan ----------------
    if (tid < NBLK) { sf0[tid] = yMg[tid]; sf1[tid] = yBg[tid]; }
    __syncthreads();
    for (int off = 1; off < NBLK; off <<= 1) {
        int act = (tid < NBLK) && (tid >= off);
        float pM = 1.f, pB = 0.f, mM = 1.f, mB = 0.f;
        if (act) { pM = sf0[tid-off]; pB = sf1[tid-off]; mM = sf0[tid]; mB = sf1[tid]; }
        __syncthreads();
        if (act) { mB = mM * pB + mB; mM = mM * pM; sf0[tid] = mM; sf1[tid] = mB; }
        __syncthreads();
    }
    const float y_blk = (b > 0) ? sf1[b-1] : 0.f;
    const float y_in = tyM * y_blk + tyB;

    // ---------------- W4: y, loss (lc-known), pending, lc setter agg ----------------
    float loss = 0.f, cnt = 0.f;
    int seen = 0; float lc = 0.f;
    int hasPend = 0, pendGood = 0, pendY05 = 0; float pendE = 0.f;
    {
        float yv[CH];
        float y = y_in; int c = c_in, ts = ts_in, lf = lf_in;
        float pu = up_prev0, puu = u_prev0;
        #pragma unroll
        for (int j = 0; j < CH; ++j) {
            int t = base + j;
            float x = upv[j];
            bool cross = (pu < 0.5f) && (x >= 0.5f);
            if (cross) c = t;
            float uph = uphv[j];
            float al  = alv[j];
            bool end    = (pu >= 0.5f) && (x < 0.5f);
            bool freeze = (x >= 0.5f) && (c > 0) && ((t - c) > MAXF);
            float yr = al * uph + (1.f - al) * y;
            float yt = end ? 0.f : (freeze ? y : yr);
            yv[j] = yt;
            if (puu == 0.f && uv[j] == 1.f) ts = t;
            bool islab = labv[j] >= 0.5f;
            if (islab && x >= 0.5f) lf = t;
            if (end) {
                int dur = lf - ts + 1;
                bool good = (dur >= 3) && (dur <= 40);
                if (islab) {
                    // lc_used = -1 -> neither case fires
                } else if (seen) {
                    float lcu = lc;
                    if (lcu != -1.f && lcu != 0.f && good) { loss += lcu; cnt += 1.f; }
                    if (lcu == 0.f && y >= 0.5f) {
                        int d = t - c; int idx = (d < MAXF) ? d : (MAXF - 1); idx = idx < 0 ? 0 : idx;
                        float df = y - sth2[idx]; loss += df * df; cnt += 1.f;
                    }
                } else {
                    hasPend = 1; pendGood = good ? 1 : 0; pendY05 = (y >= 0.5f) ? 1 : 0;
                    int d = t - c; int idx = (d < MAXF) ? d : (MAXF - 1); idx = idx < 0 ? 0 : idx;
                    float df = y - sth2[idx]; pendE = df * df;
                }
                lc = 0.f; seen = 1;
            } else if (islab) {
                lc = (x < 0.5f) ? -1.f : (yt - labv[j]) * (yt - labv[j]);
                seen = 1;
            }
            y = yt; pu = x; puu = uv[j];
        }
        *(float4*)(out + base)     = make_float4(yv[0],yv[1],yv[2],yv[3]);
        *(float4*)(out + base + 4) = make_float4(yv[4],yv[5],yv[6],yv[7]);
    }
    __syncthreads();
    si0[tid] = seen; sf0[tid] = lc;
    __syncthreads();
    {
        int mh = seen; float mv = lc;
        for (int off = 1; off < THREADS; off <<= 1) {
            int ph = 0; float pv = 0.f;
            if (tid >= off) { ph = si0[tid-off]; pv = sf0[tid-off]; }
            __syncthreads();
            if (tid >= off) { if (!mh) { mh = ph; mv = pv; } si0[tid] = mh; sf0[tid] = mv; }
            __syncthreads();
        }
    }
    const int   tlh = tid ? si0[tid-1] : 0;
    const float tlv = tid ? sf0[tid-1] : 0.f;
    if (tid == THREADS-1) { lcHg[b] = si0[tid]; lcVg[b] = sf0[tid]; }
    gb_wait(ctr + 3);

    // ---------------- R4: global lc scan + W5: resolve pendings, reduce ----------------
    if (tid < NBLK) { si0[tid] = lcHg[tid]; sf0[tid] = lcVg[tid]; }
    __syncthreads();
    for (int off = 1; off < NBLK; off <<= 1) {
        int act = (tid < NBLK) && (tid >= off);
        int ph = 0, mh = 0; float pv = 0.f, mv = 0.f;
        if (act) { ph = si0[tid-off]; pv = sf0[tid-off]; mh = si0[tid]; mv = sf0[tid]; }
        __syncthreads();
        if (act) { if (!mh) { mh = ph; mv = pv; } si0[tid] = mh; sf0[tid] = mv; }
        __syncthreads();
    }
    float lc_blk = 0.f;
    if (b > 0) { int gh = si0[b-1]; float gv = sf0[b-1]; lc_blk = gh ? gv : 0.f; }
    const float lc_in = tlh ? tlv : lc_blk;
    if (hasPend) {
        if (lc_in != -1.f && lc_in != 0.f && pendGood) { loss += lc_in; cnt += 1.f; }
        if (lc_in == 0.f && pendY05)                   { loss += pendE; cnt += 1.f; }
    }
    __syncthreads();
    sf0[tid] = loss; sf1[tid] = cnt;
    __syncthreads();
    for (int off = THREADS / 2; off > 0; off >>= 1) {
        if (tid < off) { sf0[tid] += sf0[tid + off]; sf1[tid] += sf1[tid + off]; }
        __syncthreads();
    }
    if (tid == 0) { lossB[b] = sf0[0]; cntB[b] = sf1[0]; }

    if (b == 0) {
        gb_wait(ctr + 4);
        float L = 0.f, C = 0.f;
        if (tid < NBLK) { L = lossB[tid]; C = cntB[tid]; }
        __syncthreads();
        sf0[tid] = L; sf1[tid] = C;
        __syncthreads();
        for (int off = THREADS / 2; off > 0; off >>= 1) {
            if (tid < off) { sf0[tid] += sf0[tid + off]; sf1[tid] += sf1[tid + off]; }
            __syncthreads();
        }
        if (tid == 0) { out[3 * T] = sf0[0]; out[3 * T + 1] = sf1[0]; }
    } else {
        // arrival only — no need to spin
        __threadfence();
        __syncthreads();
        if (tid == 0)
            __hip_atomic_fetch_add(ctr + 4, 1u, __ATOMIC_ACQ_REL, __HIP_MEMORY_SCOPE_AGENT);
    }
}

extern "C" void kernel_launch(void* const* d_in, const int* in_sizes, int n_in,
                              void* d_out, int out_size, void* d_ws, size_t ws_size,
                              hipStream_t stream) {
    const float* a   = (const float*)d_in[0];
    const float* u   = (const float*)d_in[1];
    const float* up  = (const float*)d_in[2];
    const float* lab = (const float*)d_in[3];
    const float* th2 = (const float*)d_in[4];
    float* out = (float*)d_out;
    const int T = in_sizes[0];

    unsigned* ctr = (unsigned*)d_ws;
    float* W = (float*)d_ws + 32;   // 128B offset for aggregate arrays

    hipMemsetAsync(d_ws, 0, 32 * sizeof(unsigned), stream);
    tg_fused<<<NBLK, THREADS, 0, stream>>>(a, u, up, lab, th2, out, T, ctr, W);
}

// Round 4
// 50.102 us; speedup vs baseline: 18.2931x; 2.4252x over previous
//
#include <hip/hip_runtime.h>

// TransformerTGNN scan — single fused persistent kernel.
// R3 change (only): cheap grid barrier. The R2 barrier used acquire atomic
// loads in the spin loop (each emits buffer_inv sc1 = full L2 invalidate on
// gfx950) plus per-thread __threadfence() (buffer_wbl2+inv per thread) ->
// ~25us/barrier. New protocol: syncthreads (drains stores to L2) ->
// fetch_add RELEASE by tid0 (one buffer_wbl2/block) -> RELAXED spin ->
// one ACQUIRE load (one buffer_inv/block) -> syncthreads.

#define THREADS 256
#define NBLK    128
#define CH      8
#define MAXF    20

__device__ __forceinline__ void gb_wait(unsigned* c) {
    __syncthreads();   // compiler emits s_waitcnt vmcnt(0) before s_barrier
    if (threadIdx.x == 0) {
        __hip_atomic_fetch_add(c, 1u, __ATOMIC_RELEASE, __HIP_MEMORY_SCOPE_AGENT);
        while (__hip_atomic_load(c, __ATOMIC_RELAXED, __HIP_MEMORY_SCOPE_AGENT) < NBLK)
            __builtin_amdgcn_s_sleep(2);
        (void)__hip_atomic_load(c, __ATOMIC_ACQUIRE, __HIP_MEMORY_SCOPE_AGENT);
    }
    __syncthreads();
}

__device__ __forceinline__ void gb_arrive(unsigned* c) {
    __syncthreads();
    if (threadIdx.x == 0)
        __hip_atomic_fetch_add(c, 1u, __ATOMIC_RELEASE, __HIP_MEMORY_SCOPE_AGENT);
}

__global__ void __launch_bounds__(THREADS, 1)
tg_fused(const float* __restrict__ ga, const float* __restrict__ gu,
         const float* __restrict__ gup, const float* __restrict__ glab,
         const float* __restrict__ gth2, float* __restrict__ out, int T,
         unsigned* __restrict__ ctr, float* __restrict__ W)
{
    int*   evH  = (int*)(W + 0 * NBLK);
    float* evM  =        W + 1 * NBLK;
    int*   evC  = (int*)(W + 2 * NBLK);
    int*   evU  = (int*)(W + 3 * NBLK);
    int*   evL  = (int*)(W + 4 * NBLK);
    float* aMg  =        W + 5 * NBLK;
    float* aBg  =        W + 6 * NBLK;
    float* yMg  =        W + 7 * NBLK;
    float* yBg  =        W + 8 * NBLK;
    int*   lcHg = (int*)(W + 9 * NBLK);
    float* lcVg =        W + 10 * NBLK;
    float* lossB =       W + 11 * NBLK;
    float* cntB  =       W + 12 * NBLK;

    const int tid = threadIdx.x, b = blockIdx.x;
    const int p = b * THREADS + tid;
    const int base = p * CH;

    __shared__ float sf0[THREADS], sf1[THREADS];
    __shared__ int si0[THREADS], si1[THREADS], si2[THREADS], si3[THREADS];
    __shared__ float sth2[MAXF];
    if (tid < MAXF) sth2[tid] = gth2[tid];

    // ---------------- W1: load inputs ----------------
    float upv[CH], uv[CH], labv[CH], av[CH];
    {
        float4 t0 = *(const float4*)(gup + base);
        float4 t1 = *(const float4*)(gup + base + 4);
        upv[0]=t0.x; upv[1]=t0.y; upv[2]=t0.z; upv[3]=t0.w;
        upv[4]=t1.x; upv[5]=t1.y; upv[6]=t1.z; upv[7]=t1.w;
        t0 = *(const float4*)(gu + base);  t1 = *(const float4*)(gu + base + 4);
        uv[0]=t0.x; uv[1]=t0.y; uv[2]=t0.z; uv[3]=t0.w;
        uv[4]=t1.x; uv[5]=t1.y; uv[6]=t1.z; uv[7]=t1.w;
        t0 = *(const float4*)(glab + base); t1 = *(const float4*)(glab + base + 4);
        labv[0]=t0.x; labv[1]=t0.y; labv[2]=t0.z; labv[3]=t0.w;
        labv[4]=t1.x; labv[5]=t1.y; labv[6]=t1.z; labv[7]=t1.w;
        t0 = *(const float4*)(ga + base);  t1 = *(const float4*)(ga + base + 4);
        av[0]=t0.x; av[1]=t0.y; av[2]=t0.z; av[3]=t0.w;
        av[4]=t1.x; av[5]=t1.y; av[6]=t1.z; av[7]=t1.w;
    }
    const float up_prev0 = base ? gup[base - 1] : 0.f;
    const float u_prev0  = base ? gu[base - 1]  : 0.f;

    // events thread aggregate
    int th = 0, tc = 0, tlu = -1, tll = -1; float tm = 0.f;
    {
        float pu = up_prev0, puu = u_prev0;
        #pragma unroll
        for (int j = 0; j < CH; ++j) {
            float x = upv[j];
            bool cross = (pu < 0.5f) && (x >= 0.5f);
            if (cross) { th = 1; tc = base + j; tm = x; } else tm = fmaxf(tm, x);
            if (puu == 0.f && uv[j] == 1.f) tlu = base + j;
            if (labv[j] >= 0.5f && x >= 0.5f) tll = base + j;
            pu = x; puu = uv[j];
        }
    }
    // block inclusive scan (events monoid)
    si0[tid] = th; sf0[tid] = tm; si1[tid] = tc; si2[tid] = tlu; si3[tid] = tll;
    __syncthreads();
    {
        int mh = th; float mm = tm; int mc = tc, mu = tlu, ml = tll;
        for (int off = 1; off < THREADS; off <<= 1) {
            int ph = 0; float pm = 0.f; int pc = 0, pqu = -1, pql = -1;
            if (tid >= off) { ph = si0[tid-off]; pm = sf0[tid-off]; pc = si1[tid-off];
                              pqu = si2[tid-off]; pql = si3[tid-off]; }
            __syncthreads();
            if (tid >= off) {
                if (!mh) { mm = fmaxf(pm, mm); mc = pc; mh = ph; }
                if (mu < 0) mu = pqu;
                if (ml < 0) ml = pql;
                si0[tid] = mh; sf0[tid] = mm; si1[tid] = mc; si2[tid] = mu; si3[tid] = ml;
            }
            __syncthreads();
        }
    }
    const int   xh  = tid ? si0[tid-1] : 0;
    const float xm  = tid ? sf0[tid-1] : 0.f;
    const int   xc  = tid ? si1[tid-1] : 0;
    const int   xlu = tid ? si2[tid-1] : -1;
    const int   xll = tid ? si3[tid-1] : -1;
    if (tid == THREADS-1) { evH[b]=si0[tid]; evM[b]=sf0[tid]; evC[b]=si1[tid];
                            evU[b]=si2[tid]; evL[b]=si3[tid]; }
    gb_wait(ctr + 0);

    // ---------------- R1: redundant global events scan ----------------
    if (tid < NBLK) { si0[tid]=evH[tid]; sf0[tid]=evM[tid]; si1[tid]=evC[tid];
                      si2[tid]=evU[tid]; si3[tid]=evL[tid]; }
    __syncthreads();
    for (int off = 1; off < NBLK; off <<= 1) {
        int ph=0, pc=0, pqu=-1, pql=-1; float pm=0.f; int act = (tid < NBLK) && (tid >= off);
        int mh=0, mc=0, mu=-1, ml=-1; float mm=0.f;
        if (act) { ph=si0[tid-off]; pm=sf0[tid-off]; pc=si1[tid-off]; pqu=si2[tid-off]; pql=si3[tid-off];
                   mh=si0[tid]; mm=sf0[tid]; mc=si1[tid]; mu=si2[tid]; ml=si3[tid]; }
        __syncthreads();
        if (act) {
            if (!mh) { mm = fmaxf(pm, mm); mc = pc; mh = ph; }
            if (mu < 0) mu = pqu;
            if (ml < 0) ml = pql;
            si0[tid]=mh; sf0[tid]=mm; si1[tid]=mc; si2[tid]=mu; si3[tid]=ml;
        }
        __syncthreads();
    }
    float blk_m = 0.f; int blk_c = 0, blk_ts = 0, blk_lf = 0;
    if (b > 0) {
        int gh = si0[b-1]; float gm = sf0[b-1]; int gc = si1[b-1], gqu = si2[b-1], gql = si3[b-1];
        blk_m = gm; blk_c = gh ? gc : 0;
        blk_ts = (gqu >= 0) ? gqu : 0; blk_lf = (gql >= 0) ? gql : 0;
    }
    const float m_in  = xh ? xm : fmaxf(blk_m, xm);
    const int   c_in  = xh ? xc : blk_c;
    const int   ts_in = (xlu >= 0) ? xlu : blk_ts;
    const int   lf_in = (xll >= 0) ? xll : blk_lf;

    // ---------------- W2: up_hat + alpha affine agg ----------------
    float uphv[CH];
    float MA = 1.f, BA = 0.f;
    {
        float m = m_in; float pu = up_prev0;
        #pragma unroll
        for (int j = 0; j < CH; ++j) {
            float x = upv[j];
            bool cross = (pu < 0.5f) && (x >= 0.5f);
            m = cross ? x : fmaxf(m, x);
            float uph = (x >= 0.5f) ? m : x;
            uphv[j] = uph;
            BA = uph * BA + (1.f - uph) * av[j];
            MA = uph * MA;
            pu = x;
        }
        *(float4*)(out + 2*T + base)     = make_float4(uphv[0],uphv[1],uphv[2],uphv[3]);
        *(float4*)(out + 2*T + base + 4) = make_float4(uphv[4],uphv[5],uphv[6],uphv[7]);
    }
    __syncthreads();
    sf0[tid] = MA; sf1[tid] = BA;
    __syncthreads();
    {
        float mM = MA, mB = BA;
        for (int off = 1; off < THREADS; off <<= 1) {
            float pM = 1.f, pB = 0.f;
            if (tid >= off) { pM = sf0[tid-off]; pB = sf1[tid-off]; }
            __syncthreads();
            if (tid >= off) { mB = mM * pB + mB; mM = mM * pM; sf0[tid] = mM; sf1[tid] = mB; }
            __syncthreads();
        }
    }
    const float txM = tid ? sf0[tid-1] : 1.f;
    const float txB = tid ? sf1[tid-1] : 0.f;
    if (tid == THREADS-1) { aMg[b] = sf0[tid]; aBg[b] = sf1[tid]; }
    gb_wait(ctr + 1);

    // ---------------- R2: global alpha affine scan ----------------
    if (tid < NBLK) { sf0[tid] = aMg[tid]; sf1[tid] = aBg[tid]; }
    __syncthreads();
    for (int off = 1; off < NBLK; off <<= 1) {
        int act = (tid < NBLK) && (tid >= off);
        float pM = 1.f, pB = 0.f, mM = 1.f, mB = 0.f;
        if (act) { pM = sf0[tid-off]; pB = sf1[tid-off]; mM = sf0[tid]; mB = sf1[tid]; }
        __syncthreads();
        if (act) { mB = mM * pB + mB; mM = mM * pM; sf0[tid] = mM; sf1[tid] = mB; }
        __syncthreads();
    }
    const float a_blk = (b > 0) ? sf1[b-1] : 0.f;
    const float alpha_in = txM * a_blk + txB;

    // ---------------- W3: alpha + y affine agg ----------------
    float alv[CH];
    float MY = 1.f, BY = 0.f;
    {
        float al = alpha_in; int c = c_in; float pu = up_prev0;
        #pragma unroll
        for (int j = 0; j < CH; ++j) {
            int t = base + j;
            float x = upv[j];
            bool cross = (pu < 0.5f) && (x >= 0.5f);
            if (cross) c = t;
            float uph = uphv[j];
            al = uph * al + (1.f - uph) * av[j];
            alv[j] = al;
            bool end    = (pu >= 0.5f) && (x < 0.5f);
            bool freeze = (x >= 0.5f) && (c > 0) && ((t - c) > MAXF);
            float A, B;
            if (end)         { A = 0.f;      B = 0.f; }
            else if (freeze) { A = 1.f;      B = 0.f; }
            else             { A = 1.f - al; B = al * uph; }
            BY = A * BY + B;
            MY = A * MY;
            pu = x;
        }
        *(float4*)(out + T + base)     = make_float4(alv[0],alv[1],alv[2],alv[3]);
        *(float4*)(out + T + base + 4) = make_float4(alv[4],alv[5],alv[6],alv[7]);
    }
    __syncthreads();
    sf0[tid] = MY; sf1[tid] = BY;
    __syncthreads();
    {
        float mM = MY, mB = BY;
        for (int off = 1; off < THREADS; off <<= 1) {
            float pM = 1.f, pB = 0.f;
            if (tid >= off) { pM = sf0[tid-off]; pB = sf1[tid-off]; }
            __syncthreads();
            if (tid >= off) { mB = mM * pB + mB; mM = mM * pM; sf0[tid] = mM; sf1[tid] = mB; }
            __syncthreads();
        }
    }
    const float tyM = tid ? sf0[tid-1] : 1.f;
    const float tyB = tid ? sf1[tid-1] : 0.f;
    if (tid == THREADS-1) { yMg[b] = sf0[tid]; yBg[b] = sf1[tid]; }
    gb_wait(ctr + 2);

    // ---------------- R3: global y affine scan ----------------
    if (tid < NBLK) { sf0[tid] = yMg[tid]; sf1[tid] = yBg[tid]; }
    __syncthreads();
    for (int off = 1; off < NBLK; off <<= 1) {
        int act = (tid < NBLK) && (tid >= off);
        float pM = 1.f, pB = 0.f, mM = 1.f, mB = 0.f;
        if (act) { pM = sf0[tid-off]; pB = sf1[tid-off]; mM = sf0[tid]; mB = sf1[tid]; }
        __syncthreads();
        if (act) { mB = mM * pB + mB; mM = mM * pM; sf0[tid] = mM; sf1[tid] = mB; }
        __syncthreads();
    }
    const float y_blk = (b > 0) ? sf1[b-1] : 0.f;
    const float y_in = tyM * y_blk + tyB;

    // ---------------- W4: y, loss (lc-known), pending, lc setter agg ----------------
    float loss = 0.f, cnt = 0.f;
    int seen = 0; float lc = 0.f;
    int hasPend = 0, pendGood = 0, pendY05 = 0; float pendE = 0.f;
    {
        float yv[CH];
        float y = y_in; int c = c_in, ts = ts_in, lf = lf_in;
        float pu = up_prev0, puu = u_prev0;
        #pragma unroll
        for (int j = 0; j < CH; ++j) {
            int t = base + j;
            float x = upv[j];
            bool cross = (pu < 0.5f) && (x >= 0.5f);
            if (cross) c = t;
            float uph = uphv[j];
            float al  = alv[j];
            bool end    = (pu >= 0.5f) && (x < 0.5f);
            bool freeze = (x >= 0.5f) && (c > 0) && ((t - c) > MAXF);
            float yr = al * uph + (1.f - al) * y;
            float yt = end ? 0.f : (freeze ? y : yr);
            yv[j] = yt;
            if (puu == 0.f && uv[j] == 1.f) ts = t;
            bool islab = labv[j] >= 0.5f;
            if (islab && x >= 0.5f) lf = t;
            if (end) {
                int dur = lf - ts + 1;
                bool good = (dur >= 3) && (dur <= 40);
                if (islab) {
                    // lc_used = -1 -> neither loss case fires
                } else if (seen) {
                    float lcu = lc;
                    if (lcu != -1.f && lcu != 0.f && good) { loss += lcu; cnt += 1.f; }
                    if (lcu == 0.f && y >= 0.5f) {
                        int d = t - c; int idx = (d < MAXF) ? d : (MAXF - 1); idx = idx < 0 ? 0 : idx;
                        float df = y - sth2[idx]; loss += df * df; cnt += 1.f;
                    }
                } else {
                    hasPend = 1; pendGood = good ? 1 : 0; pendY05 = (y >= 0.5f) ? 1 : 0;
                    int d = t - c; int idx = (d < MAXF) ? d : (MAXF - 1); idx = idx < 0 ? 0 : idx;
                    float df = y - sth2[idx]; pendE = df * df;
                }
                lc = 0.f; seen = 1;
            } else if (islab) {
                lc = (x < 0.5f) ? -1.f : (yt - labv[j]) * (yt - labv[j]);
                seen = 1;
            }
            y = yt; pu = x; puu = uv[j];
        }
        *(float4*)(out + base)     = make_float4(yv[0],yv[1],yv[2],yv[3]);
        *(float4*)(out + base + 4) = make_float4(yv[4],yv[5],yv[6],yv[7]);
    }
    __syncthreads();
    si0[tid] = seen; sf0[tid] = lc;
    __syncthreads();
    {
        int mh = seen; float mv = lc;
        for (int off = 1; off < THREADS; off <<= 1) {
            int ph = 0; float pv = 0.f;
            if (tid >= off) { ph = si0[tid-off]; pv = sf0[tid-off]; }
            __syncthreads();
            if (tid >= off) { if (!mh) { mh = ph; mv = pv; } si0[tid] = mh; sf0[tid] = mv; }
            __syncthreads();
        }
    }
    const int   tlh = tid ? si0[tid-1] : 0;
    const float tlv = tid ? sf0[tid-1] : 0.f;
    if (tid == THREADS-1) { lcHg[b] = si0[tid]; lcVg[b] = sf0[tid]; }
    gb_wait(ctr + 3);

    // ---------------- R4: global lc scan + W5: resolve pendings, reduce ----------------
    if (tid < NBLK) { si0[tid] = lcHg[tid]; sf0[tid] = lcVg[tid]; }
    __syncthreads();
    for (int off = 1; off < NBLK; off <<= 1) {
        int act = (tid < NBLK) && (tid >= off);
        int ph = 0, mh = 0; float pv = 0.f, mv = 0.f;
        if (act) { ph = si0[tid-off]; pv = sf0[tid-off]; mh = si0[tid]; mv = sf0[tid]; }
        __syncthreads();
        if (act) { if (!mh) { mh = ph; mv = pv; } si0[tid] = mh; sf0[tid] = mv; }
        __syncthreads();
    }
    float lc_blk = 0.f;
    if (b > 0) { int gh = si0[b-1]; float gv = sf0[b-1]; lc_blk = gh ? gv : 0.f; }
    const float lc_in = tlh ? tlv : lc_blk;
    if (hasPend) {
        if (lc_in != -1.f && lc_in != 0.f && pendGood) { loss += lc_in; cnt += 1.f; }
        if (lc_in == 0.f && pendY05)                   { loss += pendE; cnt += 1.f; }
    }
    __syncthreads();
    sf0[tid] = loss; sf1[tid] = cnt;
    __syncthreads();
    for (int off = THREADS / 2; off > 0; off >>= 1) {
        if (tid < off) { sf0[tid] += sf0[tid + off]; sf1[tid] += sf1[tid + off]; }
        __syncthreads();
    }
    if (tid == 0) { lossB[b] = sf0[0]; cntB[b] = sf1[0]; }

    if (b == 0) {
        gb_wait(ctr + 4);
        float L = 0.f, C = 0.f;
        if (tid < NBLK) { L = lossB[tid]; C = cntB[tid]; }
        __syncthreads();
        sf0[tid] = L; sf1[tid] = C;
        __syncthreads();
        for (int off = THREADS / 2; off > 0; off >>= 1) {
            if (tid < off) { sf0[tid] += sf0[tid + off]; sf1[tid] += sf1[tid + off]; }
            __syncthreads();
        }
        if (tid == 0) { out[3 * T] = sf0[0]; out[3 * T + 1] = sf1[0]; }
    } else {
        gb_arrive(ctr + 4);
    }
}

extern "C" void kernel_launch(void* const* d_in, const int* in_sizes, int n_in,
                              void* d_out, int out_size, void* d_ws, size_t ws_size,
                              hipStream_t stream) {
    const float* a   = (const float*)d_in[0];
    const float* u   = (const float*)d_in[1];
    const float* up  = (const float*)d_in[2];
    const float* lab = (const float*)d_in[3];
    const float* th2 = (const float*)d_in[4];
    float* out = (float*)d_out;
    const int T = in_sizes[0];

    unsigned* ctr = (unsigned*)d_ws;
    float* W = (float*)d_ws + 32;   // 128B offset for aggregate arrays

    hipMemsetAsync(d_ws, 0, 32 * sizeof(unsigned), stream);
    tg_fused<<<NBLK, THREADS, 0, stream>>>(a, u, up, lab, th2, out, T, ctr, W);
}

// Round 5
// 36.324 us; speedup vs baseline: 25.2317x; 1.3793x over previous
//
#include <hip/hip_runtime.h>

// TransformerTGNN scan — single fused persistent kernel.
// R4 change (only): zero-cache-maintenance cross-block communication.
//   R3 profile: 56us at 1.7% VALU / 1.2% HBM -> stalled on buffer_inv sc1
//   (agent acquire = full XCD-L2 invalidate) and buffer_wbl2 (agent release =
//   full L2 writeback incl. the 3MB of out) x 128 blocks x 5 barriers.
//   Fix: all cross-block aggregates are accessed ONLY via RELAXED agent-scope
//   atomic load/store (= sc1 global ops, L2-bypass, MALL-coherent). Barrier is
//   RELAXED fetch_add + RELAXED spin; __syncthreads' vmcnt(0) drain orders the
//   sc1 stores before arrival; the counter data-dependency orders the reads.
//   No inv, no wbl2 anywhere.

#define THREADS 256
#define NBLK    128
#define CH      8
#define MAXF    20

#define AST(p, v)  __hip_atomic_store((p), (v), __ATOMIC_RELAXED, __HIP_MEMORY_SCOPE_AGENT)
#define ALD(p)     __hip_atomic_load((p), __ATOMIC_RELAXED, __HIP_MEMORY_SCOPE_AGENT)

__device__ __forceinline__ void gb_wait(unsigned* c) {
    __syncthreads();   // emits s_waitcnt vmcnt(0) -> sc1 stores ack'd at MALL
    if (threadIdx.x == 0) {
        __hip_atomic_fetch_add(c, 1u, __ATOMIC_RELAXED, __HIP_MEMORY_SCOPE_AGENT);
        while (__hip_atomic_load(c, __ATOMIC_RELAXED, __HIP_MEMORY_SCOPE_AGENT) < NBLK)
            __builtin_amdgcn_s_sleep(1);
    }
    __syncthreads();
}

__device__ __forceinline__ void gb_arrive(unsigned* c) {
    __syncthreads();
    if (threadIdx.x == 0)
        __hip_atomic_fetch_add(c, 1u, __ATOMIC_RELAXED, __HIP_MEMORY_SCOPE_AGENT);
}

__global__ void __launch_bounds__(THREADS, 1)
tg_fused(const float* __restrict__ ga, const float* __restrict__ gu,
         const float* __restrict__ gup, const float* __restrict__ glab,
         const float* __restrict__ gth2, float* __restrict__ out, int T,
         unsigned* __restrict__ ctr, float* __restrict__ W)
{
    int*   evH  = (int*)(W + 0 * NBLK);
    float* evM  =        W + 1 * NBLK;
    int*   evC  = (int*)(W + 2 * NBLK);
    int*   evU  = (int*)(W + 3 * NBLK);
    int*   evL  = (int*)(W + 4 * NBLK);
    float* aMg  =        W + 5 * NBLK;
    float* aBg  =        W + 6 * NBLK;
    float* yMg  =        W + 7 * NBLK;
    float* yBg  =        W + 8 * NBLK;
    int*   lcHg = (int*)(W + 9 * NBLK);
    float* lcVg =        W + 10 * NBLK;
    float* lossB =       W + 11 * NBLK;
    float* cntB  =       W + 12 * NBLK;

    const int tid = threadIdx.x, b = blockIdx.x;
    const int p = b * THREADS + tid;
    const int base = p * CH;

    __shared__ float sf0[THREADS], sf1[THREADS];
    __shared__ int si0[THREADS], si1[THREADS], si2[THREADS], si3[THREADS];
    __shared__ float sth2[MAXF];
    if (tid < MAXF) sth2[tid] = gth2[tid];

    // ---------------- W1: load inputs ----------------
    float upv[CH], uv[CH], labv[CH], av[CH];
    {
        float4 t0 = *(const float4*)(gup + base);
        float4 t1 = *(const float4*)(gup + base + 4);
        upv[0]=t0.x; upv[1]=t0.y; upv[2]=t0.z; upv[3]=t0.w;
        upv[4]=t1.x; upv[5]=t1.y; upv[6]=t1.z; upv[7]=t1.w;
        t0 = *(const float4*)(gu + base);  t1 = *(const float4*)(gu + base + 4);
        uv[0]=t0.x; uv[1]=t0.y; uv[2]=t0.z; uv[3]=t0.w;
        uv[4]=t1.x; uv[5]=t1.y; uv[6]=t1.z; uv[7]=t1.w;
        t0 = *(const float4*)(glab + base); t1 = *(const float4*)(glab + base + 4);
        labv[0]=t0.x; labv[1]=t0.y; labv[2]=t0.z; labv[3]=t0.w;
        labv[4]=t1.x; labv[5]=t1.y; labv[6]=t1.z; labv[7]=t1.w;
        t0 = *(const float4*)(ga + base);  t1 = *(const float4*)(ga + base + 4);
        av[0]=t0.x; av[1]=t0.y; av[2]=t0.z; av[3]=t0.w;
        av[4]=t1.x; av[5]=t1.y; av[6]=t1.z; av[7]=t1.w;
    }
    const float up_prev0 = base ? gup[base - 1] : 0.f;
    const float u_prev0  = base ? gu[base - 1]  : 0.f;

    // events thread aggregate
    int th = 0, tc = 0, tlu = -1, tll = -1; float tm = 0.f;
    {
        float pu = up_prev0, puu = u_prev0;
        #pragma unroll
        for (int j = 0; j < CH; ++j) {
            float x = upv[j];
            bool cross = (pu < 0.5f) && (x >= 0.5f);
            if (cross) { th = 1; tc = base + j; tm = x; } else tm = fmaxf(tm, x);
            if (puu == 0.f && uv[j] == 1.f) tlu = base + j;
            if (labv[j] >= 0.5f && x >= 0.5f) tll = base + j;
            pu = x; puu = uv[j];
        }
    }
    // block inclusive scan (events monoid)
    si0[tid] = th; sf0[tid] = tm; si1[tid] = tc; si2[tid] = tlu; si3[tid] = tll;
    __syncthreads();
    {
        int mh = th; float mm = tm; int mc = tc, mu = tlu, ml = tll;
        for (int off = 1; off < THREADS; off <<= 1) {
            int ph = 0; float pm = 0.f; int pc = 0, pqu = -1, pql = -1;
            if (tid >= off) { ph = si0[tid-off]; pm = sf0[tid-off]; pc = si1[tid-off];
                              pqu = si2[tid-off]; pql = si3[tid-off]; }
            __syncthreads();
            if (tid >= off) {
                if (!mh) { mm = fmaxf(pm, mm); mc = pc; mh = ph; }
                if (mu < 0) mu = pqu;
                if (ml < 0) ml = pql;
                si0[tid] = mh; sf0[tid] = mm; si1[tid] = mc; si2[tid] = mu; si3[tid] = ml;
            }
            __syncthreads();
        }
    }
    const int   xh  = tid ? si0[tid-1] : 0;
    const float xm  = tid ? sf0[tid-1] : 0.f;
    const int   xc  = tid ? si1[tid-1] : 0;
    const int   xlu = tid ? si2[tid-1] : -1;
    const int   xll = tid ? si3[tid-1] : -1;
    if (tid == THREADS-1) {
        AST(&evH[b], si0[tid]); AST(&evM[b], sf0[tid]); AST(&evC[b], si1[tid]);
        AST(&evU[b], si2[tid]); AST(&evL[b], si3[tid]);
    }
    gb_wait(ctr + 0);

    // ---------------- R1: redundant global events scan ----------------
    if (tid < NBLK) { si0[tid]=ALD(&evH[tid]); sf0[tid]=ALD(&evM[tid]); si1[tid]=ALD(&evC[tid]);
                      si2[tid]=ALD(&evU[tid]); si3[tid]=ALD(&evL[tid]); }
    __syncthreads();
    for (int off = 1; off < NBLK; off <<= 1) {
        int ph=0, pc=0, pqu=-1, pql=-1; float pm=0.f; int act = (tid < NBLK) && (tid >= off);
        int mh=0, mc=0, mu=-1, ml=-1; float mm=0.f;
        if (act) { ph=si0[tid-off]; pm=sf0[tid-off]; pc=si1[tid-off]; pqu=si2[tid-off]; pql=si3[tid-off];
                   mh=si0[tid]; mm=sf0[tid]; mc=si1[tid]; mu=si2[tid]; ml=si3[tid]; }
        __syncthreads();
        if (act) {
            if (!mh) { mm = fmaxf(pm, mm); mc = pc; mh = ph; }
            if (mu < 0) mu = pqu;
            if (ml < 0) ml = pql;
            si0[tid]=mh; sf0[tid]=mm; si1[tid]=mc; si2[tid]=mu; si3[tid]=ml;
        }
        __syncthreads();
    }
    float blk_m = 0.f; int blk_c = 0, blk_ts = 0, blk_lf = 0;
    if (b > 0) {
        int gh = si0[b-1]; float gm = sf0[b-1]; int gc = si1[b-1], gqu = si2[b-1], gql = si3[b-1];
        blk_m = gm; blk_c = gh ? gc : 0;
        blk_ts = (gqu >= 0) ? gqu : 0; blk_lf = (gql >= 0) ? gql : 0;
    }
    const float m_in  = xh ? xm : fmaxf(blk_m, xm);
    const int   c_in  = xh ? xc : blk_c;
    const int   ts_in = (xlu >= 0) ? xlu : blk_ts;
    const int   lf_in = (xll >= 0) ? xll : blk_lf;

    // ---------------- W2: up_hat + alpha affine agg ----------------
    float uphv[CH];
    float MA = 1.f, BA = 0.f;
    {
        float m = m_in; float pu = up_prev0;
        #pragma unroll
        for (int j = 0; j < CH; ++j) {
            float x = upv[j];
            bool cross = (pu < 0.5f) && (x >= 0.5f);
            m = cross ? x : fmaxf(m, x);
            float uph = (x >= 0.5f) ? m : x;
            uphv[j] = uph;
            BA = uph * BA + (1.f - uph) * av[j];
            MA = uph * MA;
            pu = x;
        }
        *(float4*)(out + 2*T + base)     = make_float4(uphv[0],uphv[1],uphv[2],uphv[3]);
        *(float4*)(out + 2*T + base + 4) = make_float4(uphv[4],uphv[5],uphv[6],uphv[7]);
    }
    __syncthreads();
    sf0[tid] = MA; sf1[tid] = BA;
    __syncthreads();
    {
        float mM = MA, mB = BA;
        for (int off = 1; off < THREADS; off <<= 1) {
            float pM = 1.f, pB = 0.f;
            if (tid >= off) { pM = sf0[tid-off]; pB = sf1[tid-off]; }
            __syncthreads();
            if (tid >= off) { mB = mM * pB + mB; mM = mM * pM; sf0[tid] = mM; sf1[tid] = mB; }
            __syncthreads();
        }
    }
    const float txM = tid ? sf0[tid-1] : 1.f;
    const float txB = tid ? sf1[tid-1] : 0.f;
    if (tid == THREADS-1) { AST(&aMg[b], sf0[tid]); AST(&aBg[b], sf1[tid]); }
    gb_wait(ctr + 1);

    // ---------------- R2: global alpha affine scan ----------------
    if (tid < NBLK) { sf0[tid] = ALD(&aMg[tid]); sf1[tid] = ALD(&aBg[tid]); }
    __syncthreads();
    for (int off = 1; off < NBLK; off <<= 1) {
        int act = (tid < NBLK) && (tid >= off);
        float pM = 1.f, pB = 0.f, mM = 1.f, mB = 0.f;
        if (act) { pM = sf0[tid-off]; pB = sf1[tid-off]; mM = sf0[tid]; mB = sf1[tid]; }
        __syncthreads();
        if (act) { mB = mM * pB + mB; mM = mM * pM; sf0[tid] = mM; sf1[tid] = mB; }
        __syncthreads();
    }
    const float a_blk = (b > 0) ? sf1[b-1] : 0.f;
    const float alpha_in = txM * a_blk + txB;

    // ---------------- W3: alpha + y affine agg ----------------
    float alv[CH];
    float MY = 1.f, BY = 0.f;
    {
        float al = alpha_in; int c = c_in; float pu = up_prev0;
        #pragma unroll
        for (int j = 0; j < CH; ++j) {
            int t = base + j;
            float x = upv[j];
            bool cross = (pu < 0.5f) && (x >= 0.5f);
            if (cross) c = t;
            float uph = uphv[j];
            al = uph * al + (1.f - uph) * av[j];
            alv[j] = al;
            bool end    = (pu >= 0.5f) && (x < 0.5f);
            bool freeze = (x >= 0.5f) && (c > 0) && ((t - c) > MAXF);
            float A, B;
            if (end)         { A = 0.f;      B = 0.f; }
            else if (freeze) { A = 1.f;      B = 0.f; }
            else             { A = 1.f - al; B = al * uph; }
            BY = A * BY + B;
            MY = A * MY;
            pu = x;
        }
        *(float4*)(out + T + base)     = make_float4(alv[0],alv[1],alv[2],alv[3]);
        *(float4*)(out + T + base + 4) = make_float4(alv[4],alv[5],alv[6],alv[7]);
    }
    __syncthreads();
    sf0[tid] = MY; sf1[tid] = BY;
    __syncthreads();
    {
        float mM = MY, mB = BY;
        for (int off = 1; off < THREADS; off <<= 1) {
            float pM = 1.f, pB = 0.f;
            if (tid >= off) { pM = sf0[tid-off]; pB = sf1[tid-off]; }
            __syncthreads();
            if (tid >= off) { mB = mM * pB + mB; mM = mM * pM; sf0[tid] = mM; sf1[tid] = mB; }
            __syncthreads();
        }
    }
    const float tyM = tid ? sf0[tid-1] : 1.f;
    const float tyB = tid ? sf1[tid-1] : 0.f;
    if (tid == THREADS-1) { AST(&yMg[b], sf0[tid]); AST(&yBg[b], sf1[tid]); }
    gb_wait(ctr + 2);

    // ---------------- R3: global y affine scan ----------------
    if (tid < NBLK) { sf0[tid] = ALD(&yMg[tid]); sf1[tid] = ALD(&yBg[tid]); }
    __syncthreads();
    for (int off = 1; off < NBLK; off <<= 1) {
        int act = (tid < NBLK) && (tid >= off);
        float pM = 1.f, pB = 0.f, mM = 1.f, mB = 0.f;
        if (act) { pM = sf0[tid-off]; pB = sf1[tid-off]; mM = sf0[tid]; mB = sf1[tid]; }
        __syncthreads();
        if (act) { mB = mM * pB + mB; mM = mM * pM; sf0[tid] = mM; sf1[tid] = mB; }
        __syncthreads();
    }
    const float y_blk = (b > 0) ? sf1[b-1] : 0.f;
    const float y_in = tyM * y_blk + tyB;

    // ---------------- W4: y, loss (lc-known), pending, lc setter agg ----------------
    float loss = 0.f, cnt = 0.f;
    int seen = 0; float lc = 0.f;
    int hasPend = 0, pendGood = 0, pendY05 = 0; float pendE = 0.f;
    {
        float yv[CH];
        float y = y_in; int c = c_in, ts = ts_in, lf = lf_in;
        float pu = up_prev0, puu = u_prev0;
        #pragma unroll
        for (int j = 0; j < CH; ++j) {
            int t = base + j;
            float x = upv[j];
            bool cross = (pu < 0.5f) && (x >= 0.5f);
            if (cross) c = t;
            float uph = uphv[j];
            float al  = alv[j];
            bool end    = (pu >= 0.5f) && (x < 0.5f);
            bool freeze = (x >= 0.5f) && (c > 0) && ((t - c) > MAXF);
            float yr = al * uph + (1.f - al) * y;
            float yt = end ? 0.f : (freeze ? y : yr);
            yv[j] = yt;
            if (puu == 0.f && uv[j] == 1.f) ts = t;
            bool islab = labv[j] >= 0.5f;
            if (islab && x >= 0.5f) lf = t;
            if (end) {
                int dur = lf - ts + 1;
                bool good = (dur >= 3) && (dur <= 40);
                if (islab) {
                    // lc_used = -1 -> neither loss case fires
                } else if (seen) {
                    float lcu = lc;
                    if (lcu != -1.f && lcu != 0.f && good) { loss += lcu; cnt += 1.f; }
                    if (lcu == 0.f && y >= 0.5f) {
                        int d = t - c; int idx = (d < MAXF) ? d : (MAXF - 1); idx = idx < 0 ? 0 : idx;
                        float df = y - sth2[idx]; loss += df * df; cnt += 1.f;
                    }
                } else {
                    hasPend = 1; pendGood = good ? 1 : 0; pendY05 = (y >= 0.5f) ? 1 : 0;
                    int d = t - c; int idx = (d < MAXF) ? d : (MAXF - 1); idx = idx < 0 ? 0 : idx;
                    float df = y - sth2[idx]; pendE = df * df;
                }
                lc = 0.f; seen = 1;
            } else if (islab) {
                lc = (x < 0.5f) ? -1.f : (yt - labv[j]) * (yt - labv[j]);
                seen = 1;
            }
            y = yt; pu = x; puu = uv[j];
        }
        *(float4*)(out + base)     = make_float4(yv[0],yv[1],yv[2],yv[3]);
        *(float4*)(out + base + 4) = make_float4(yv[4],yv[5],yv[6],yv[7]);
    }
    __syncthreads();
    si0[tid] = seen; sf0[tid] = lc;
    __syncthreads();
    {
        int mh = seen; float mv = lc;
        for (int off = 1; off < THREADS; off <<= 1) {
            int ph = 0; float pv = 0.f;
            if (tid >= off) { ph = si0[tid-off]; pv = sf0[tid-off]; }
            __syncthreads();
            if (tid >= off) { if (!mh) { mh = ph; mv = pv; } si0[tid] = mh; sf0[tid] = mv; }
            __syncthreads();
        }
    }
    const int   tlh = tid ? si0[tid-1] : 0;
    const float tlv = tid ? sf0[tid-1] : 0.f;
    if (tid == THREADS-1) { AST(&lcHg[b], si0[tid]); AST(&lcVg[b], sf0[tid]); }
    gb_wait(ctr + 3);

    // ---------------- R4: global lc scan + W5: resolve pendings, reduce ----------------
    if (tid < NBLK) { si0[tid] = ALD(&lcHg[tid]); sf0[tid] = ALD(&lcVg[tid]); }
    __syncthreads();
    for (int off = 1; off < NBLK; off <<= 1) {
        int act = (tid < NBLK) && (tid >= off);
        int ph = 0, mh = 0; float pv = 0.f, mv = 0.f;
        if (act) { ph = si0[tid-off]; pv = sf0[tid-off]; mh = si0[tid]; mv = sf0[tid]; }
        __syncthreads();
        if (act) { if (!mh) { mh = ph; mv = pv; } si0[tid] = mh; sf0[tid] = mv; }
        __syncthreads();
    }
    float lc_blk = 0.f;
    if (b > 0) { int gh = si0[b-1]; float gv = sf0[b-1]; lc_blk = gh ? gv : 0.f; }
    const float lc_in = tlh ? tlv : lc_blk;
    if (hasPend) {
        if (lc_in != -1.f && lc_in != 0.f && pendGood) { loss += lc_in; cnt += 1.f; }
        if (lc_in == 0.f && pendY05)                   { loss += pendE; cnt += 1.f; }
    }
    __syncthreads();
    sf0[tid] = loss; sf1[tid] = cnt;
    __syncthreads();
    for (int off = THREADS / 2; off > 0; off >>= 1) {
        if (tid < off) { sf0[tid] += sf0[tid + off]; sf1[tid] += sf1[tid + off]; }
        __syncthreads();
    }
    if (tid == 0) { AST(&lossB[b], sf0[0]); AST(&cntB[b], sf1[0]); }

    if (b == 0) {
        gb_wait(ctr + 4);
        float L = 0.f, C = 0.f;
        if (tid < NBLK) { L = ALD(&lossB[tid]); C = ALD(&cntB[tid]); }
        __syncthreads();
        sf0[tid] = L; sf1[tid] = C;
        __syncthreads();
        for (int off = THREADS / 2; off > 0; off >>= 1) {
            if (tid < off) { sf0[tid] += sf0[tid + off]; sf1[tid] += sf1[tid + off]; }
            __syncthreads();
        }
        if (tid == 0) { out[3 * T] = sf0[0]; out[3 * T + 1] = sf1[0]; }
    } else {
        gb_arrive(ctr + 4);
    }
}

extern "C" void kernel_launch(void* const* d_in, const int* in_sizes, int n_in,
                              void* d_out, int out_size, void* d_ws, size_t ws_size,
                              hipStream_t stream) {
    const float* a   = (const float*)d_in[0];
    const float* u   = (const float*)d_in[1];
    const float* up  = (const float*)d_in[2];
    const float* lab = (const float*)d_in[3];
    const float* th2 = (const float*)d_in[4];
    float* out = (float*)d_out;
    const int T = in_sizes[0];

    unsigned* ctr = (unsigned*)d_ws;
    float* W = (float*)d_ws + 32;   // 128B offset for aggregate arrays

    hipMemsetAsync(d_ws, 0, 32 * sizeof(unsigned), stream);
    tg_fused<<<NBLK, THREADS, 0, stream>>>(a, u, up, lab, th2, out, T, ctr, W);
}

// Round 6
// 29.540 us; speedup vs baseline: 31.0264x; 1.2297x over previous
//
#include <hip/hip_runtime.h>

// TransformerTGNN scan — single fused persistent kernel, R5.
// Changes vs R4 (all latency-chain, per post-mortem: 2% VALU / 1.4% HBM = stall-bound):
//   1) all block/grid scans are wave-shuffle scans (__shfl_up), ~15 syncthreads total
//      instead of ~120 from LDS Hillis-Steele.
//   2) NBLK 128->64 (CH=16): grid scans fit exactly one wave; half the barrier arrivals.
//   3) 5th barrier removed: unresolved pendings in a block all share the same incoming
//      lc (no setter in their block prefix), so each block publishes closed-form
//      (lossKnown, cntKnown, PG, PE, PY); non-zero blocks arrive-and-exit at barrier 3;
//      block 0 resolves lc scan + final reduction alone.
// Cross-block traffic stays RELAXED agent-scope sc1 (no buffer_inv/wbl2).

#define THREADS 256
#define NBLK    64
#define CH      16
#define MAXF    20

#define AST(p, v)  __hip_atomic_store((p), (v), __ATOMIC_RELAXED, __HIP_MEMORY_SCOPE_AGENT)
#define ALD(p)     __hip_atomic_load((p), __ATOMIC_RELAXED, __HIP_MEMORY_SCOPE_AGENT)

__device__ __forceinline__ void gb_wait(unsigned* c) {
    __syncthreads();   // drains this wave's stores (vmcnt 0) before arrival
    if (threadIdx.x == 0) {
        __hip_atomic_fetch_add(c, 1u, __ATOMIC_RELAXED, __HIP_MEMORY_SCOPE_AGENT);
        while (__hip_atomic_load(c, __ATOMIC_RELAXED, __HIP_MEMORY_SCOPE_AGENT) < NBLK)
            __builtin_amdgcn_s_sleep(1);
    }
    __syncthreads();
}

__device__ __forceinline__ void gb_arrive(unsigned* c) {
    __syncthreads();
    if (threadIdx.x == 0)
        __hip_atomic_fetch_add(c, 1u, __ATOMIC_RELAXED, __HIP_MEMORY_SCOPE_AGENT);
}

__global__ void __launch_bounds__(THREADS, 1)
tg_fused(const float* __restrict__ ga, const float* __restrict__ gu,
         const float* __restrict__ gup, const float* __restrict__ glab,
         const float* __restrict__ gth2, float* __restrict__ out, int T,
         unsigned* __restrict__ ctr, float* __restrict__ W)
{
    int*   evH  = (int*)(W + 0 * NBLK);
    float* evM  =        W + 1 * NBLK;
    int*   evC  = (int*)(W + 2 * NBLK);
    int*   evU  = (int*)(W + 3 * NBLK);
    int*   evL  = (int*)(W + 4 * NBLK);
    float* aMg  =        W + 5 * NBLK;
    float* aBg  =        W + 6 * NBLK;
    float* yMg  =        W + 7 * NBLK;
    float* yBg  =        W + 8 * NBLK;
    int*   lcHg = (int*)(W + 9 * NBLK);
    float* lcVg =        W + 10 * NBLK;
    float* loK  =        W + 11 * NBLK;
    float* cnK  =        W + 12 * NBLK;
    float* pGg  =        W + 13 * NBLK;
    float* pEg  =        W + 14 * NBLK;
    float* pYg  =        W + 15 * NBLK;

    const int tid  = threadIdx.x, b = blockIdx.x;
    const int lane = tid & 63,  wid = tid >> 6;
    const int base = (b * THREADS + tid) * CH;

    __shared__ int   sWH[4], sWC[4], sWU[4], sWL[4];
    __shared__ float sWM[4], sWB[4];
    __shared__ float sP0[4], sP1[4], sP2[4], sP3[4], sP4[4];
    __shared__ int   sGH[NBLK], sGC[NBLK], sGU[NBLK], sGL[NBLK];
    __shared__ float sGM[NBLK], sGB[NBLK];
    __shared__ float sth2[MAXF];
    if (tid < MAXF) sth2[tid] = gth2[tid];

    // ---------------- W1: load inputs ----------------
    float upv[CH], uv[CH], labv[CH], av[CH];
    #pragma unroll
    for (int q = 0; q < CH / 4; ++q) {
        float4 t;
        t = ((const float4*)(gup + base))[q];
        upv[4*q]=t.x; upv[4*q+1]=t.y; upv[4*q+2]=t.z; upv[4*q+3]=t.w;
        t = ((const float4*)(gu + base))[q];
        uv[4*q]=t.x; uv[4*q+1]=t.y; uv[4*q+2]=t.z; uv[4*q+3]=t.w;
        t = ((const float4*)(glab + base))[q];
        labv[4*q]=t.x; labv[4*q+1]=t.y; labv[4*q+2]=t.z; labv[4*q+3]=t.w;
        t = ((const float4*)(ga + base))[q];
        av[4*q]=t.x; av[4*q+1]=t.y; av[4*q+2]=t.z; av[4*q+3]=t.w;
    }
    const float up_prev0 = base ? gup[base - 1] : 0.f;
    const float u_prev0  = base ? gu[base - 1]  : 0.f;

    // events thread aggregate (invariant: c==0 while h==0)
    int th = 0, tc = 0, tlu = -1, tll = -1; float tm = 0.f;
    {
        float pu = up_prev0, puu = u_prev0;
        #pragma unroll
        for (int j = 0; j < CH; ++j) {
            float x = upv[j];
            bool cross = (pu < 0.5f) && (x >= 0.5f);
            if (cross) { th = 1; tc = base + j; tm = x; } else tm = fmaxf(tm, x);
            if (puu == 0.f && uv[j] == 1.f) tlu = base + j;
            if (labv[j] >= 0.5f && x >= 0.5f) tll = base + j;
            pu = x; puu = uv[j];
        }
    }
    // wave inclusive scan (events monoid)
    int ih = th, ic = tc, iu = tlu, il = tll; float im = tm;
    #pragma unroll
    for (int off = 1; off < 64; off <<= 1) {
        int   ph = __shfl_up(ih, off, 64);
        float pm = __shfl_up(im, off, 64);
        int   pc = __shfl_up(ic, off, 64);
        int   pu = __shfl_up(iu, off, 64);
        int   pl = __shfl_up(il, off, 64);
        if (lane >= off) {
            if (!ih) { im = fmaxf(pm, im); ic = pc; ih = ph; }
            if (iu < 0) iu = pu;
            if (il < 0) il = pl;
        }
    }
    int eh = __shfl_up(ih, 1, 64), ec = __shfl_up(ic, 1, 64);
    int eu2 = __shfl_up(iu, 1, 64), el2 = __shfl_up(il, 1, 64);
    float em = __shfl_up(im, 1, 64);
    if (lane == 0) { eh = 0; em = 0.f; ec = 0; eu2 = -1; el2 = -1; }
    if (lane == 63) { sWH[wid]=ih; sWM[wid]=im; sWC[wid]=ic; sWU[wid]=iu; sWL[wid]=il; }
    __syncthreads();
    int wh = 0, wc2 = 0, wu = -1, wl = -1; float wm = 0.f;
    for (int w = 0; w < wid; ++w) {
        int hh = sWH[w]; float mm = sWM[w];
        if (hh) { wh = 1; wm = mm; wc2 = sWC[w]; } else wm = fmaxf(wm, mm);
        int su = sWU[w]; if (su >= 0) wu = su;
        int sl = sWL[w]; if (sl >= 0) wl = sl;
    }
    int xh, xc; float xm;
    if (eh) { xh = 1; xm = em; xc = ec; } else { xh = wh; xm = fmaxf(wm, em); xc = wc2; }
    const int xlu = (eu2 >= 0) ? eu2 : wu;
    const int xll = (el2 >= 0) ? el2 : wl;
    if (tid == THREADS - 1) {
        int BH, BC; float BM;
        if (ih) { BH = 1; BM = im; BC = ic; } else { BH = wh; BM = fmaxf(wm, im); BC = wc2; }
        int BU = (iu >= 0) ? iu : wu, BL = (il >= 0) ? il : wl;
        AST(&evH[b], BH); AST(&evM[b], BM); AST(&evC[b], BC);
        AST(&evU[b], BU); AST(&evL[b], BL);
    }
    gb_wait(ctr + 0);

    // ---------------- R1: grid events scan (one wave) ----------------
    if (tid < NBLK) {
        int h = ALD(&evH[tid]); float m = ALD(&evM[tid]);
        int cc = ALD(&evC[tid]), uu = ALD(&evU[tid]), ll = ALD(&evL[tid]);
        #pragma unroll
        for (int off = 1; off < 64; off <<= 1) {
            int   ph = __shfl_up(h,  off, 64);
            float pm = __shfl_up(m,  off, 64);
            int   pc = __shfl_up(cc, off, 64);
            int   pu = __shfl_up(uu, off, 64);
            int   pl = __shfl_up(ll, off, 64);
            if (lane >= off) {
                if (!h) { m = fmaxf(pm, m); cc = pc; h = ph; }
                if (uu < 0) uu = pu;
                if (ll < 0) ll = pl;
            }
        }
        sGH[tid] = h; sGM[tid] = m; sGC[tid] = cc; sGU[tid] = uu; sGL[tid] = ll;
    }
    __syncthreads();
    float bm = 0.f; int bc = 0, bu = -1, bl = -1;
    if (b > 0) { bm = sGM[b-1]; bc = sGC[b-1]; bu = sGU[b-1]; bl = sGL[b-1]; }
    const float m_in  = xh ? xm : fmaxf(bm, xm);
    const int   c_in  = xh ? xc : bc;                    // c==0 when h==0 invariant
    const int   ts_in = (xlu >= 0) ? xlu : ((bu >= 0) ? bu : 0);
    const int   lf_in = (xll >= 0) ? xll : ((bl >= 0) ? bl : 0);

    // ---------------- W2: up_hat + alpha affine ----------------
    float uphv[CH];
    float MA = 1.f, BA = 0.f;
    {
        float m = m_in, pu = up_prev0;
        #pragma unroll
        for (int j = 0; j < CH; ++j) {
            float x = upv[j];
            bool cross = (pu < 0.5f) && (x >= 0.5f);
            m = cross ? x : fmaxf(m, x);
            float uph = (x >= 0.5f) ? m : x;
            uphv[j] = uph;
            BA = uph * BA + (1.f - uph) * av[j];
            MA = uph * MA;
            pu = x;
        }
        #pragma unroll
        for (int q = 0; q < CH / 4; ++q)
            ((float4*)(out + 2*T + base))[q] =
                make_float4(uphv[4*q], uphv[4*q+1], uphv[4*q+2], uphv[4*q+3]);
    }
    float iM = MA, iB = BA;
    #pragma unroll
    for (int off = 1; off < 64; off <<= 1) {
        float pM = __shfl_up(iM, off, 64), pB = __shfl_up(iB, off, 64);
        if (lane >= off) { iB = iM * pB + iB; iM = iM * pM; }
    }
    float eM = __shfl_up(iM, 1, 64), eB = __shfl_up(iB, 1, 64);
    if (lane == 0) { eM = 1.f; eB = 0.f; }
    if (lane == 63) { sWM[wid] = iM; sWB[wid] = iB; }
    __syncthreads();
    float wM = 1.f, wB = 0.f;
    for (int w = 0; w < wid; ++w) { float cM = sWM[w], cB = sWB[w]; wB = cM * wB + cB; wM = cM * wM; }
    const float txM = eM * wM, txB = eM * wB + eB;
    if (tid == THREADS - 1) { AST(&aMg[b], iM * wM); AST(&aBg[b], iM * wB + iB); }
    gb_wait(ctr + 1);

    // ---------------- R2: grid alpha scan ----------------
    if (tid < NBLK) {
        float M2 = ALD(&aMg[tid]), B2 = ALD(&aBg[tid]);
        #pragma unroll
        for (int off = 1; off < 64; off <<= 1) {
            float pM = __shfl_up(M2, off, 64), pB = __shfl_up(B2, off, 64);
            if (lane >= off) { B2 = M2 * pB + B2; M2 = M2 * pM; }
        }
        sGB[tid] = B2;
    }
    __syncthreads();
    const float a_blk = (b > 0) ? sGB[b-1] : 0.f;
    const float alpha_in = txM * a_blk + txB;

    // ---------------- W3: alpha + y affine ----------------
    float alv[CH];
    float MY = 1.f, BY = 0.f;
    {
        float al = alpha_in; int c = c_in; float pu = up_prev0;
        #pragma unroll
        for (int j = 0; j < CH; ++j) {
            int t = base + j;
            float x = upv[j];
            bool cross = (pu < 0.5f) && (x >= 0.5f);
            if (cross) c = t;
            float uph = uphv[j];
            al = uph * al + (1.f - uph) * av[j];
            alv[j] = al;
            bool end    = (pu >= 0.5f) && (x < 0.5f);
            bool freeze = (x >= 0.5f) && (c > 0) && ((t - c) > MAXF);
            float A, B;
            if (end)         { A = 0.f;      B = 0.f; }
            else if (freeze) { A = 1.f;      B = 0.f; }
            else             { A = 1.f - al; B = al * uph; }
            BY = A * BY + B;
            MY = A * MY;
            pu = x;
        }
        #pragma unroll
        for (int q = 0; q < CH / 4; ++q)
            ((float4*)(out + T + base))[q] =
                make_float4(alv[4*q], alv[4*q+1], alv[4*q+2], alv[4*q+3]);
    }
    float jM = MY, jB = BY;
    #pragma unroll
    for (int off = 1; off < 64; off <<= 1) {
        float pM = __shfl_up(jM, off, 64), pB = __shfl_up(jB, off, 64);
        if (lane >= off) { jB = jM * pB + jB; jM = jM * pM; }
    }
    float fM = __shfl_up(jM, 1, 64), fB = __shfl_up(jB, 1, 64);
    if (lane == 0) { fM = 1.f; fB = 0.f; }
    if (lane == 63) { sWM[wid] = jM; sWB[wid] = jB; }
    __syncthreads();
    float vM = 1.f, vB = 0.f;
    for (int w = 0; w < wid; ++w) { float cM = sWM[w], cB = sWB[w]; vB = cM * vB + cB; vM = cM * vM; }
    const float tyM = fM * vM, tyB = fM * vB + fB;
    if (tid == THREADS - 1) { AST(&yMg[b], jM * vM); AST(&yBg[b], jM * vB + jB); }
    gb_wait(ctr + 2);

    // ---------------- R3: grid y scan ----------------
    if (tid < NBLK) {
        float M2 = ALD(&yMg[tid]), B2 = ALD(&yBg[tid]);
        #pragma unroll
        for (int off = 1; off < 64; off <<= 1) {
            float pM = __shfl_up(M2, off, 64), pB = __shfl_up(B2, off, 64);
            if (lane >= off) { B2 = M2 * pB + B2; M2 = M2 * pM; }
        }
        sGB[tid] = B2;
    }
    __syncthreads();
    const float y_blk = (b > 0) ? sGB[b-1] : 0.f;
    const float y_in = tyM * y_blk + tyB;

    // ---------------- W4: y + loss + lc setter (invariant: lc==0 while seen==0) ----------------
    float loss = 0.f, cnt = 0.f;
    int seen = 0; float lc = 0.f;
    int hasPend = 0, pendGood = 0, pendY05 = 0; float pendE = 0.f;
    {
        float yv[CH];
        float y = y_in; int c = c_in, ts = ts_in, lf = lf_in;
        float pu = up_prev0, puu = u_prev0;
        #pragma unroll
        for (int j = 0; j < CH; ++j) {
            int t = base + j;
            float x = upv[j];
            bool cross = (pu < 0.5f) && (x >= 0.5f);
            if (cross) c = t;
            float uph = uphv[j];
            float al  = alv[j];
            bool end    = (pu >= 0.5f) && (x < 0.5f);
            bool freeze = (x >= 0.5f) && (c > 0) && ((t - c) > MAXF);
            float yr = al * uph + (1.f - al) * y;
            float yt = end ? 0.f : (freeze ? y : yr);
            yv[j] = yt;
            if (puu == 0.f && uv[j] == 1.f) ts = t;
            bool islab = labv[j] >= 0.5f;
            if (islab && x >= 0.5f) lf = t;
            if (end) {
                int dur = lf - ts + 1;
                bool good = (dur >= 3) && (dur <= 40);
                if (islab) {
                    // lc_used = -1 -> no loss case fires
                } else if (seen) {
                    float lcu = lc;
                    if (lcu != -1.f && lcu != 0.f && good) { loss += lcu; cnt += 1.f; }
                    if (lcu == 0.f && y >= 0.5f) {
                        int d = t - c; int idx = (d < MAXF) ? d : (MAXF - 1); idx = idx < 0 ? 0 : idx;
                        float df = y - sth2[idx]; loss += df * df; cnt += 1.f;
                    }
                } else {
                    hasPend = 1; pendGood = good ? 1 : 0; pendY05 = (y >= 0.5f) ? 1 : 0;
                    int d = t - c; int idx = (d < MAXF) ? d : (MAXF - 1); idx = idx < 0 ? 0 : idx;
                    float df = y - sth2[idx]; pendE = df * df;
                }
                lc = 0.f; seen = 1;
            } else if (islab) {
                lc = (x < 0.5f) ? -1.f : (yt - labv[j]) * (yt - labv[j]);
                seen = 1;
            }
            y = yt; pu = x; puu = uv[j];
        }
        #pragma unroll
        for (int q = 0; q < CH / 4; ++q)
            ((float4*)(out + base))[q] =
                make_float4(yv[4*q], yv[4*q+1], yv[4*q+2], yv[4*q+3]);
    }
    // wave lc scan
    int is_ = seen; float iv = lc;
    #pragma unroll
    for (int off = 1; off < 64; off <<= 1) {
        int ph = __shfl_up(is_, off, 64); float pv = __shfl_up(iv, off, 64);
        if (lane >= off && !is_) { is_ = ph; iv = pv; }
    }
    int es = __shfl_up(is_, 1, 64); float ev = __shfl_up(iv, 1, 64);
    if (lane == 0) { es = 0; ev = 0.f; }
    if (lane == 63) { sWH[wid] = is_; sWB[wid] = iv; }
    __syncthreads();
    int ws = 0; float wv = 0.f;
    for (int w = 0; w < wid; ++w) { if (sWH[w]) { ws = 1; wv = sWB[w]; } }
    const int   tlh = es ? 1  : ws;
    const float tlv = es ? ev : wv;
    if (tid == THREADS - 1) {
        int BS = is_ ? 1 : ws; float BV = is_ ? iv : wv;
        AST(&lcHg[b], BS); AST(&lcVg[b], BV);
    }
    // resolve pendings (local if a setter exists in block prefix; else closed-form publish)
    float PGl = 0.f, PEl = 0.f, PYl = 0.f;
    if (hasPend) {
        if (tlh) {
            float lcv = tlv;
            if (lcv == 0.f) { if (pendY05) { loss += pendE; cnt += 1.f; } }
            else if (lcv != -1.f) { if (pendGood) { loss += lcv; cnt += 1.f; } }
        } else {
            PGl = pendGood ? 1.f : 0.f;
            PYl = pendY05 ? 1.f : 0.f;
            PEl = pendY05 ? pendE : 0.f;
        }
    }
    float rL = loss, rC = cnt, rG = PGl, rE = PEl, rY = PYl;
    #pragma unroll
    for (int off = 32; off; off >>= 1) {
        rL += __shfl_xor(rL, off, 64); rC += __shfl_xor(rC, off, 64);
        rG += __shfl_xor(rG, off, 64); rE += __shfl_xor(rE, off, 64);
        rY += __shfl_xor(rY, off, 64);
    }
    if (lane == 0) { sP0[wid] = rL; sP1[wid] = rC; sP2[wid] = rG; sP3[wid] = rE; sP4[wid] = rY; }
    __syncthreads();
    if (tid == 0) {
        AST(&loK[b], sP0[0] + sP0[1] + sP0[2] + sP0[3]);
        AST(&cnK[b], sP1[0] + sP1[1] + sP1[2] + sP1[3]);
        AST(&pGg[b], sP2[0] + sP2[1] + sP2[2] + sP2[3]);
        AST(&pEg[b], sP3[0] + sP3[1] + sP3[2] + sP3[3]);
        AST(&pYg[b], sP4[0] + sP4[1] + sP4[2] + sP4[3]);
    }

    if (b == 0) {
        gb_wait(ctr + 3);
        if (tid < NBLK) {
            int h = ALD(&lcHg[tid]); float v = ALD(&lcVg[tid]);
            #pragma unroll
            for (int off = 1; off < 64; off <<= 1) {
                int ph = __shfl_up(h, off, 64); float pv = __shfl_up(v, off, 64);
                if (lane >= off && !h) { h = ph; v = pv; }
            }
            float ev3 = __shfl_up(v, 1, 64);
            float lcb = (lane == 0) ? 0.f : ev3;   // v==0 while h==0 invariant
            float Lb = ALD(&loK[tid]), Cb = ALD(&cnK[tid]);
            float G = ALD(&pGg[tid]), E = ALD(&pEg[tid]), Y = ALD(&pYg[tid]);
            if (lcb == 0.f) { Lb += E; Cb += Y; }
            else if (lcb != -1.f) { Lb += lcb * G; Cb += G; }
            #pragma unroll
            for (int off = 32; off; off >>= 1) {
                Lb += __shfl_xor(Lb, off, 64); Cb += __shfl_xor(Cb, off, 64);
            }
            if (tid == 0) { out[3 * T] = Lb; out[3 * T + 1] = Cb; }
        }
    } else {
        gb_arrive(ctr + 3);
    }
}

extern "C" void kernel_launch(void* const* d_in, const int* in_sizes, int n_in,
                              void* d_out, int out_size, void* d_ws, size_t ws_size,
                              hipStream_t stream) {
    const float* a   = (const float*)d_in[0];
    const float* u   = (const float*)d_in[1];
    const float* up  = (const float*)d_in[2];
    const float* lab = (const float*)d_in[3];
    const float* th2 = (const float*)d_in[4];
    float* out = (float*)d_out;
    const int T = in_sizes[0];

    unsigned* ctr = (unsigned*)d_ws;
    float* W = (float*)d_ws + 32;   // 128B offset for aggregate arrays

    hipMemsetAsync(d_ws, 0, 32 * sizeof(unsigned), stream);
    tg_fused<<<NBLK, THREADS, 0, stream>>>(a, u, up, lab, th2, out, T, ctr, W);
}

// Round 8
// 28.670 us; speedup vs baseline: 31.9684x; 1.0304x over previous
//
#include <hip/hip_runtime.h>

// TransformerTGNN scan — single fused persistent kernel, R7 (= R6 + compile fix:
// renamed R1 block-prefix locals that shadowed the 'gu' kernel parameter).
// R5 post-mortem: memory-LATENCY-bound (93-113 GB/s on 5.5MB, VALU 1.2%) —
// NBLK=64 used only 64 CUs x 4 waves -> ~1MB in flight -> ~250 GB/s ceiling.
// R6/R7: NBLK=128 x THREADS=512 (8 waves/CU on 128 CUs), CH=4 -> ~4x in-flight
// loads. Grid scans: one wave, 2 entries/lane, EXCLUSIVE (read sG[b] direct).
// Barriers stay 4, relaxed sc1 cross-block traffic (no inv/wbl2).

#define THREADS 512
#define NBLK    128
#define CH      4
#define WPB     (THREADS / 64)   // 8 waves per block
#define MAXF    20

#define AST(p, v)  __hip_atomic_store((p), (v), __ATOMIC_RELAXED, __HIP_MEMORY_SCOPE_AGENT)
#define ALD(p)     __hip_atomic_load((p), __ATOMIC_RELAXED, __HIP_MEMORY_SCOPE_AGENT)

__device__ __forceinline__ void gb_wait(unsigned* c) {
    __syncthreads();   // drains stores (vmcnt 0) before arrival
    if (threadIdx.x == 0) {
        __hip_atomic_fetch_add(c, 1u, __ATOMIC_RELAXED, __HIP_MEMORY_SCOPE_AGENT);
        while (__hip_atomic_load(c, __ATOMIC_RELAXED, __HIP_MEMORY_SCOPE_AGENT) < NBLK)
            __builtin_amdgcn_s_sleep(1);
    }
    __syncthreads();
}

__device__ __forceinline__ void gb_arrive(unsigned* c) {
    __syncthreads();
    if (threadIdx.x == 0)
        __hip_atomic_fetch_add(c, 1u, __ATOMIC_RELAXED, __HIP_MEMORY_SCOPE_AGENT);
}

__global__ void __launch_bounds__(THREADS, 1)
tg_fused(const float* __restrict__ ga, const float* __restrict__ gu,
         const float* __restrict__ gup, const float* __restrict__ glab,
         const float* __restrict__ gth2, float* __restrict__ out, int T,
         unsigned* __restrict__ ctr, float* __restrict__ W)
{
    int*   evH  = (int*)(W + 0 * NBLK);
    float* evM  =        W + 1 * NBLK;
    int*   evC  = (int*)(W + 2 * NBLK);
    int*   evU  = (int*)(W + 3 * NBLK);
    int*   evL  = (int*)(W + 4 * NBLK);
    float* aMg  =        W + 5 * NBLK;
    float* aBg  =        W + 6 * NBLK;
    float* yMg  =        W + 7 * NBLK;
    float* yBg  =        W + 8 * NBLK;
    int*   lcHg = (int*)(W + 9 * NBLK);
    float* lcVg =        W + 10 * NBLK;
    float* loK  =        W + 11 * NBLK;
    float* cnK  =        W + 12 * NBLK;
    float* pGg  =        W + 13 * NBLK;
    float* pEg  =        W + 14 * NBLK;
    float* pYg  =        W + 15 * NBLK;

    const int tid  = threadIdx.x, b = blockIdx.x;
    const int lane = tid & 63,  wid = tid >> 6;
    const int base = (b * THREADS + tid) * CH;

    __shared__ int   sWH[WPB], sWC[WPB], sWU[WPB], sWL[WPB];
    __shared__ float sWM[WPB], sWB[WPB];
    __shared__ float sP0[WPB], sP1[WPB], sP2[WPB], sP3[WPB], sP4[WPB];
    __shared__ int   sGH[NBLK], sGC[NBLK], sGU[NBLK], sGL[NBLK];
    __shared__ float sGM[NBLK], sGB[NBLK];
    __shared__ float sth2[MAXF];
    if (tid < MAXF) sth2[tid] = gth2[tid];

    // ---------------- W1: load inputs ----------------
    float upv[CH], uv[CH], labv[CH], av[CH];
    {
        float4 t;
        t = *(const float4*)(gup + base);  upv[0]=t.x; upv[1]=t.y; upv[2]=t.z; upv[3]=t.w;
        t = *(const float4*)(gu + base);   uv[0]=t.x;  uv[1]=t.y;  uv[2]=t.z;  uv[3]=t.w;
        t = *(const float4*)(glab + base); labv[0]=t.x;labv[1]=t.y;labv[2]=t.z;labv[3]=t.w;
        t = *(const float4*)(ga + base);   av[0]=t.x;  av[1]=t.y;  av[2]=t.z;  av[3]=t.w;
    }
    const float up_prev0 = base ? gup[base - 1] : 0.f;
    const float u_prev0  = base ? gu[base - 1]  : 0.f;

    // events thread aggregate (invariant: c==0 while h==0)
    int th = 0, tc = 0, tlu = -1, tll = -1; float tm = 0.f;
    {
        float pu = up_prev0, puu = u_prev0;
        #pragma unroll
        for (int j = 0; j < CH; ++j) {
            float x = upv[j];
            bool cross = (pu < 0.5f) && (x >= 0.5f);
            if (cross) { th = 1; tc = base + j; tm = x; } else tm = fmaxf(tm, x);
            if (puu == 0.f && uv[j] == 1.f) tlu = base + j;
            if (labv[j] >= 0.5f && x >= 0.5f) tll = base + j;
            pu = x; puu = uv[j];
        }
    }
    // wave inclusive scan (events monoid)
    int ih = th, ic = tc, iu = tlu, il = tll; float im = tm;
    #pragma unroll
    for (int off = 1; off < 64; off <<= 1) {
        int   ph = __shfl_up(ih, off, 64);
        float pm = __shfl_up(im, off, 64);
        int   pc = __shfl_up(ic, off, 64);
        int   pu = __shfl_up(iu, off, 64);
        int   pl = __shfl_up(il, off, 64);
        if (lane >= off) {
            if (!ih) { im = fmaxf(pm, im); ic = pc; ih = ph; }
            if (iu < 0) iu = pu;
            if (il < 0) il = pl;
        }
    }
    int eh = __shfl_up(ih, 1, 64), ec = __shfl_up(ic, 1, 64);
    int eu2 = __shfl_up(iu, 1, 64), el2 = __shfl_up(il, 1, 64);
    float em = __shfl_up(im, 1, 64);
    if (lane == 0) { eh = 0; em = 0.f; ec = 0; eu2 = -1; el2 = -1; }
    if (lane == 63) { sWH[wid]=ih; sWM[wid]=im; sWC[wid]=ic; sWU[wid]=iu; sWL[wid]=il; }
    __syncthreads();
    int wh = 0, wc2 = 0, wu = -1, wl = -1; float wm = 0.f;
    for (int w = 0; w < wid; ++w) {
        int hh = sWH[w]; float mm = sWM[w];
        if (hh) { wh = 1; wm = mm; wc2 = sWC[w]; } else wm = fmaxf(wm, mm);
        int su = sWU[w]; if (su >= 0) wu = su;
        int sl = sWL[w]; if (sl >= 0) wl = sl;
    }
    int xh, xc; float xm;
    if (eh) { xh = 1; xm = em; xc = ec; } else { xh = wh; xm = fmaxf(wm, em); xc = wc2; }
    const int xlu = (eu2 >= 0) ? eu2 : wu;
    const int xll = (el2 >= 0) ? el2 : wl;
    if (tid == THREADS - 1) {
        int BH, BC; float BM;
        if (ih) { BH = 1; BM = im; BC = ic; } else { BH = wh; BM = fmaxf(wm, im); BC = wc2; }
        int BU = (iu >= 0) ? iu : wu, BL = (il >= 0) ? il : wl;
        AST(&evH[b], BH); AST(&evM[b], BM); AST(&evC[b], BC);
        AST(&evU[b], BU); AST(&evL[b], BL);
    }
    gb_wait(ctr + 0);

    // ---------------- R1: grid events EXCLUSIVE scan (wave 0, 2 entries/lane) ----------------
    if (tid < 64) {
        const int k0 = 2 * tid, k1 = k0 + 1;
        int h0 = ALD(&evH[k0]); float m0 = ALD(&evM[k0]);
        int c0 = ALD(&evC[k0]); int u0 = ALD(&evU[k0]); int l0 = ALD(&evL[k0]);
        int h1 = ALD(&evH[k1]); float m1 = ALD(&evM[k1]);
        int c1 = ALD(&evC[k1]); int u1 = ALD(&evU[k1]); int l1 = ALD(&evL[k1]);
        // pair aggregate = e0 then e1
        int   ah = h1 ? 1 : h0;
        float am = h1 ? m1 : fmaxf(m0, m1);
        int   ac = h1 ? c1 : c0;
        int   au = (u1 >= 0) ? u1 : u0;
        int   aL = (l1 >= 0) ? l1 : l0;
        int gih = ah, gic = ac, giu = au, gil = aL; float gim = am;
        #pragma unroll
        for (int off = 1; off < 64; off <<= 1) {
            int   ph = __shfl_up(gih, off, 64);
            float pm = __shfl_up(gim, off, 64);
            int   pc = __shfl_up(gic, off, 64);
            int   pu = __shfl_up(giu, off, 64);
            int   pl = __shfl_up(gil, off, 64);
            if (lane >= off) {
                if (!gih) { gim = fmaxf(pm, gim); gic = pc; gih = ph; }
                if (giu < 0) giu = pu;
                if (gil < 0) gil = pl;
            }
        }
        int geh = __shfl_up(gih, 1, 64), gec = __shfl_up(gic, 1, 64);
        int geu = __shfl_up(giu, 1, 64), gel = __shfl_up(gil, 1, 64);
        float gem = __shfl_up(gim, 1, 64);
        if (lane == 0) { geh = 0; gem = 0.f; gec = 0; geu = -1; gel = -1; }
        sGH[k0] = geh; sGM[k0] = gem; sGC[k0] = gec; sGU[k0] = geu; sGL[k0] = gel;
        // entry k1 exclusive = excl(k0) then e0
        int   qh = h0 ? 1 : geh;
        float qm = h0 ? m0 : fmaxf(gem, m0);
        int   qc = h0 ? c0 : gec;
        int   qu = (u0 >= 0) ? u0 : geu;
        int   ql = (l0 >= 0) ? l0 : gel;
        sGH[k1] = qh; sGM[k1] = qm; sGC[k1] = qc; sGU[k1] = qu; sGL[k1] = ql;
    }
    __syncthreads();
    const int   pgH = sGH[b]; const float pgM = sGM[b];
    const int   pgC = sGC[b]; const int pgU = sGU[b]; const int pgL = sGL[b];
    const float m_in  = xh ? xm : fmaxf(pgM, xm);
    const int   c_in  = xh ? xc : pgC;                   // c==0 when h==0 invariant
    const int   ts_in = (xlu >= 0) ? xlu : ((pgU >= 0) ? pgU : 0);
    const int   lf_in = (xll >= 0) ? xll : ((pgL >= 0) ? pgL : 0);

    // ---------------- W2: up_hat + alpha affine ----------------
    float uphv[CH];
    float MA = 1.f, BA = 0.f;
    {
        float m = m_in, pu = up_prev0;
        #pragma unroll
        for (int j = 0; j < CH; ++j) {
            float x = upv[j];
            bool cross = (pu < 0.5f) && (x >= 0.5f);
            m = cross ? x : fmaxf(m, x);
            float uph = (x >= 0.5f) ? m : x;
            uphv[j] = uph;
            BA = uph * BA + (1.f - uph) * av[j];
            MA = uph * MA;
            pu = x;
        }
        *(float4*)(out + 2*T + base) = make_float4(uphv[0], uphv[1], uphv[2], uphv[3]);
    }
    float iM = MA, iB = BA;
    #pragma unroll
    for (int off = 1; off < 64; off <<= 1) {
        float pM = __shfl_up(iM, off, 64), pB = __shfl_up(iB, off, 64);
        if (lane >= off) { iB = iM * pB + iB; iM = iM * pM; }
    }
    float eM = __shfl_up(iM, 1, 64), eB = __shfl_up(iB, 1, 64);
    if (lane == 0) { eM = 1.f; eB = 0.f; }
    if (lane == 63) { sWM[wid] = iM; sWB[wid] = iB; }
    __syncthreads();
    float wM = 1.f, wB = 0.f;
    for (int w = 0; w < wid; ++w) { float cM = sWM[w], cB = sWB[w]; wB = cM * wB + cB; wM = cM * wM; }
    const float txM = eM * wM, txB = eM * wB + eB;
    if (tid == THREADS - 1) { AST(&aMg[b], iM * wM); AST(&aBg[b], iM * wB + iB); }
    gb_wait(ctr + 1);

    // ---------------- R2: grid alpha EXCLUSIVE scan ----------------
    if (tid < 64) {
        const int k0 = 2 * tid, k1 = k0 + 1;
        float M0 = ALD(&aMg[k0]), B0 = ALD(&aBg[k0]);
        float M1 = ALD(&aMg[k1]), B1 = ALD(&aBg[k1]);
        float gM = M1 * M0, gB = M1 * B0 + B1;
        #pragma unroll
        for (int off = 1; off < 64; off <<= 1) {
            float pM = __shfl_up(gM, off, 64), pB = __shfl_up(gB, off, 64);
            if (lane >= off) { gB = gM * pB + gB; gM = gM * pM; }
        }
        float xB = __shfl_up(gB, 1, 64);
        if (lane == 0) xB = 0.f;
        sGB[k0] = xB;
        sGB[k1] = M0 * xB + B0;
    }
    __syncthreads();
    const float alpha_in = txM * sGB[b] + txB;

    // ---------------- W3: alpha + y affine ----------------
    float alv[CH];
    float MY = 1.f, BY = 0.f;
    {
        float al = alpha_in; int c = c_in; float pu = up_prev0;
        #pragma unroll
        for (int j = 0; j < CH; ++j) {
            int t = base + j;
            float x = upv[j];
            bool cross = (pu < 0.5f) && (x >= 0.5f);
            if (cross) c = t;
            float uph = uphv[j];
            al = uph * al + (1.f - uph) * av[j];
            alv[j] = al;
            bool end    = (pu >= 0.5f) && (x < 0.5f);
            bool freeze = (x >= 0.5f) && (c > 0) && ((t - c) > MAXF);
            float A, B;
            if (end)         { A = 0.f;      B = 0.f; }
            else if (freeze) { A = 1.f;      B = 0.f; }
            else             { A = 1.f - al; B = al * uph; }
            BY = A * BY + B;
            MY = A * MY;
            pu = x;
        }
        *(float4*)(out + T + base) = make_float4(alv[0], alv[1], alv[2], alv[3]);
    }
    float jM = MY, jB = BY;
    #pragma unroll
    for (int off = 1; off < 64; off <<= 1) {
        float pM = __shfl_up(jM, off, 64), pB = __shfl_up(jB, off, 64);
        if (lane >= off) { jB = jM * pB + jB; jM = jM * pM; }
    }
    float fM = __shfl_up(jM, 1, 64), fB = __shfl_up(jB, 1, 64);
    if (lane == 0) { fM = 1.f; fB = 0.f; }
    if (lane == 63) { sWM[wid] = jM; sWB[wid] = jB; }
    __syncthreads();
    float vM = 1.f, vB = 0.f;
    for (int w = 0; w < wid; ++w) { float cM = sWM[w], cB = sWB[w]; vB = cM * vB + cB; vM = cM * vM; }
    const float tyM = fM * vM, tyB = fM * vB + fB;
    if (tid == THREADS - 1) { AST(&yMg[b], jM * vM); AST(&yBg[b], jM * vB + jB); }
    gb_wait(ctr + 2);

    // ---------------- R3: grid y EXCLUSIVE scan ----------------
    if (tid < 64) {
        const int k0 = 2 * tid, k1 = k0 + 1;
        float M0 = ALD(&yMg[k0]), B0 = ALD(&yBg[k0]);
        float M1 = ALD(&yMg[k1]), B1 = ALD(&yBg[k1]);
        float gM = M1 * M0, gB = M1 * B0 + B1;
        #pragma unroll
        for (int off = 1; off < 64; off <<= 1) {
            float pM = __shfl_up(gM, off, 64), pB = __shfl_up(gB, off, 64);
            if (lane >= off) { gB = gM * pB + gB; gM = gM * pM; }
        }
        float xB = __shfl_up(gB, 1, 64);
        if (lane == 0) xB = 0.f;
        sGB[k0] = xB;
        sGB[k1] = M0 * xB + B0;
    }
    __syncthreads();
    const float y_in = tyM * sGB[b] + tyB;

    // ---------------- W4: y + loss + lc setter (invariant: lc==0 while seen==0) ----------------
    float loss = 0.f, cnt = 0.f;
    int seen = 0; float lc = 0.f;
    int hasPend = 0, pendGood = 0, pendY05 = 0; float pendE = 0.f;
    {
        float yv[CH];
        float y = y_in; int c = c_in, ts = ts_in, lf = lf_in;
        float pu = up_prev0, puu = u_prev0;
        #pragma unroll
        for (int j = 0; j < CH; ++j) {
            int t = base + j;
            float x = upv[j];
            bool cross = (pu < 0.5f) && (x >= 0.5f);
            if (cross) c = t;
            float uph = uphv[j];
            float al  = alv[j];
            bool end    = (pu >= 0.5f) && (x < 0.5f);
            bool freeze = (x >= 0.5f) && (c > 0) && ((t - c) > MAXF);
            float yr = al * uph + (1.f - al) * y;
            float yt = end ? 0.f : (freeze ? y : yr);
            yv[j] = yt;
            if (puu == 0.f && uv[j] == 1.f) ts = t;
            bool islab = labv[j] >= 0.5f;
            if (islab && x >= 0.5f) lf = t;
            if (end) {
                int dur = lf - ts + 1;
                bool good = (dur >= 3) && (dur <= 40);
                if (islab) {
                    // lc_used = -1 -> no loss case fires
                } else if (seen) {
                    float lcu = lc;
                    if (lcu != -1.f && lcu != 0.f && good) { loss += lcu; cnt += 1.f; }
                    if (lcu == 0.f && y >= 0.5f) {
                        int d = t - c; int idx = (d < MAXF) ? d : (MAXF - 1); idx = idx < 0 ? 0 : idx;
                        float df = y - sth2[idx]; loss += df * df; cnt += 1.f;
                    }
                } else {
                    hasPend = 1; pendGood = good ? 1 : 0; pendY05 = (y >= 0.5f) ? 1 : 0;
                    int d = t - c; int idx = (d < MAXF) ? d : (MAXF - 1); idx = idx < 0 ? 0 : idx;
                    float df = y - sth2[idx]; pendE = df * df;
                }
                lc = 0.f; seen = 1;
            } else if (islab) {
                lc = (x < 0.5f) ? -1.f : (yt - labv[j]) * (yt - labv[j]);
                seen = 1;
            }
            y = yt; pu = x; puu = uv[j];
        }
        *(float4*)(out + base) = make_float4(yv[0], yv[1], yv[2], yv[3]);
    }
    // block lc scan
    int is_ = seen; float iv = lc;
    #pragma unroll
    for (int off = 1; off < 64; off <<= 1) {
        int ph = __shfl_up(is_, off, 64); float pv = __shfl_up(iv, off, 64);
        if (lane >= off && !is_) { is_ = ph; iv = pv; }
    }
    int es = __shfl_up(is_, 1, 64); float evx = __shfl_up(iv, 1, 64);
    if (lane == 0) { es = 0; evx = 0.f; }
    if (lane == 63) { sWH[wid] = is_; sWB[wid] = iv; }
    __syncthreads();
    int ws = 0; float wv = 0.f;
    for (int w = 0; w < wid; ++w) { if (sWH[w]) { ws = 1; wv = sWB[w]; } }
    const int   tlh = es ? 1   : ws;
    const float tlv = es ? evx : wv;
    if (tid == THREADS - 1) {
        int BS = is_ ? 1 : ws; float BV = is_ ? iv : wv;
        AST(&lcHg[b], BS); AST(&lcVg[b], BV);
    }
    // resolve pendings (local if setter in block prefix; else closed-form publish)
    float PGl = 0.f, PEl = 0.f, PYl = 0.f;
    if (hasPend) {
        if (tlh) {
            float lcv = tlv;
            if (lcv == 0.f) { if (pendY05) { loss += pendE; cnt += 1.f; } }
            else if (lcv != -1.f) { if (pendGood) { loss += lcv; cnt += 1.f; } }
        } else {
            PGl = pendGood ? 1.f : 0.f;
            PYl = pendY05 ? 1.f : 0.f;
            PEl = pendY05 ? pendE : 0.f;
        }
    }
    float rL = loss, rC = cnt, rG = PGl, rE = PEl, rY = PYl;
    #pragma unroll
    for (int off = 32; off; off >>= 1) {
        rL += __shfl_xor(rL, off, 64); rC += __shfl_xor(rC, off, 64);
        rG += __shfl_xor(rG, off, 64); rE += __shfl_xor(rE, off, 64);
        rY += __shfl_xor(rY, off, 64);
    }
    if (lane == 0) { sP0[wid] = rL; sP1[wid] = rC; sP2[wid] = rG; sP3[wid] = rE; sP4[wid] = rY; }
    __syncthreads();
    if (tid == 0) {
        float L = 0.f, C = 0.f, G = 0.f, E = 0.f, Y = 0.f;
        #pragma unroll
        for (int w = 0; w < WPB; ++w) { L += sP0[w]; C += sP1[w]; G += sP2[w]; E += sP3[w]; Y += sP4[w]; }
        AST(&loK[b], L); AST(&cnK[b], C); AST(&pGg[b], G); AST(&pEg[b], E); AST(&pYg[b], Y);
    }

    if (b == 0) {
        gb_wait(ctr + 3);
        if (tid < 64) {
            const int k0 = 2 * tid, k1 = k0 + 1;
            int h0 = ALD(&lcHg[k0]); float v0 = ALD(&lcVg[k0]);
            int h1 = ALD(&lcHg[k1]); float v1 = ALD(&lcVg[k1]);
            int gh2 = h1 ? 1 : h0; float gv2 = h1 ? v1 : v0;
            #pragma unroll
            for (int off = 1; off < 64; off <<= 1) {
                int ph = __shfl_up(gh2, off, 64); float pv = __shfl_up(gv2, off, 64);
                if (lane >= off && !gh2) { gh2 = ph; gv2 = pv; }
            }
            float xv = __shfl_up(gv2, 1, 64);
            if (lane == 0) xv = 0.f;
            const float lcb0 = xv;                  // v==0 while h==0 invariant
            const float lcb1 = h0 ? v0 : xv;
            float Lb = ALD(&loK[k0]) + ALD(&loK[k1]);
            float Cb = ALD(&cnK[k0]) + ALD(&cnK[k1]);
            {
                float G = ALD(&pGg[k0]), E = ALD(&pEg[k0]), Y = ALD(&pYg[k0]);
                if (lcb0 == 0.f) { Lb += E; Cb += Y; }
                else if (lcb0 != -1.f) { Lb += lcb0 * G; Cb += G; }
            }
            {
                float G = ALD(&pGg[k1]), E = ALD(&pEg[k1]), Y = ALD(&pYg[k1]);
                if (lcb1 == 0.f) { Lb += E; Cb += Y; }
                else if (lcb1 != -1.f) { Lb += lcb1 * G; Cb += G; }
            }
            #pragma unroll
            for (int off = 32; off; off >>= 1) {
                Lb += __shfl_xor(Lb, off, 64); Cb += __shfl_xor(Cb, off, 64);
            }
            if (tid == 0) { out[3 * T] = Lb; out[3 * T + 1] = Cb; }
        }
    } else {
        gb_arrive(ctr + 3);
    }
}

extern "C" void kernel_launch(void* const* d_in, const int* in_sizes, int n_in,
                              void* d_out, int out_size, void* d_ws, size_t ws_size,
                              hipStream_t stream) {
    const float* a   = (const float*)d_in[0];
    const float* u   = (const float*)d_in[1];
    const float* up  = (const float*)d_in[2];
    const float* lab = (const float*)d_in[3];
    const float* th2 = (const float*)d_in[4];
    float* out = (float*)d_out;
    const int T = in_sizes[0];

    unsigned* ctr = (unsigned*)d_ws;
    float* W = (float*)d_ws + 32;   // 128B offset for aggregate arrays

    (void)hipMemsetAsync(d_ws, 0, 32 * sizeof(unsigned), stream);
    tg_fused<<<NBLK, THREADS, 0, stream>>>(a, u, up, lab, th2, out, T, ctr, W);
}

// Round 9
// 27.307 us; speedup vs baseline: 33.5640x; 1.0499x over previous
//
#include <hip/hip_runtime.h>

// TransformerTGNN scan — single fused persistent kernel, R8.
// R7 post-mortem: 4x MLP bought ~1us -> cost is fixed: launch+memset (~8-9us),
// 3 dependent MALL-barrier round trips (~3us each), irreducible work (~6us).
// R8 trims the residual: NBLK=64 x THREADS=512 (CH=8) so grid scans are exactly
// one slot per lane; prev-element via __shfl_up instead of per-thread scalar
// loads; grid-scan broadcast via single LDS scalars (lane==b writes).
// Barriers: 3 full + 1 arrive-only; relaxed sc1 cross-block traffic only.

#define THREADS 512
#define NBLK    64
#define CH      8
#define WPB     (THREADS / 64)   // 8 waves per block
#define MAXF    20

#define AST(p, v)  __hip_atomic_store((p), (v), __ATOMIC_RELAXED, __HIP_MEMORY_SCOPE_AGENT)
#define ALD(p)     __hip_atomic_load((p), __ATOMIC_RELAXED, __HIP_MEMORY_SCOPE_AGENT)

__device__ __forceinline__ void gb_wait(unsigned* c) {
    __syncthreads();   // drains stores (vmcnt 0) before arrival
    if (threadIdx.x == 0) {
        __hip_atomic_fetch_add(c, 1u, __ATOMIC_RELAXED, __HIP_MEMORY_SCOPE_AGENT);
        while (__hip_atomic_load(c, __ATOMIC_RELAXED, __HIP_MEMORY_SCOPE_AGENT) < NBLK)
            __builtin_amdgcn_s_sleep(1);
    }
    __syncthreads();
}

__device__ __forceinline__ void gb_arrive(unsigned* c) {
    __syncthreads();
    if (threadIdx.x == 0)
        __hip_atomic_fetch_add(c, 1u, __ATOMIC_RELAXED, __HIP_MEMORY_SCOPE_AGENT);
}

__global__ void __launch_bounds__(THREADS, 1)
tg_fused(const float* __restrict__ ga, const float* __restrict__ gu,
         const float* __restrict__ gup, const float* __restrict__ glab,
         const float* __restrict__ gth2, float* __restrict__ out, int T,
         unsigned* __restrict__ ctr, float* __restrict__ W)
{
    int*   evH  = (int*)(W + 0 * NBLK);
    float* evM  =        W + 1 * NBLK;
    int*   evC  = (int*)(W + 2 * NBLK);
    int*   evU  = (int*)(W + 3 * NBLK);
    int*   evL  = (int*)(W + 4 * NBLK);
    float* aMg  =        W + 5 * NBLK;
    float* aBg  =        W + 6 * NBLK;
    float* yMg  =        W + 7 * NBLK;
    float* yBg  =        W + 8 * NBLK;
    int*   lcHg = (int*)(W + 9 * NBLK);
    float* lcVg =        W + 10 * NBLK;
    float* loK  =        W + 11 * NBLK;
    float* cnK  =        W + 12 * NBLK;
    float* pGg  =        W + 13 * NBLK;
    float* pEg  =        W + 14 * NBLK;
    float* pYg  =        W + 15 * NBLK;

    const int tid  = threadIdx.x, b = blockIdx.x;
    const int lane = tid & 63,  wid = tid >> 6;
    const int base = (b * THREADS + tid) * CH;

    __shared__ int   sWH[WPB], sWC[WPB], sWU[WPB], sWL[WPB];
    __shared__ float sWM[WPB], sWB[WPB];
    __shared__ float sP0[WPB], sP1[WPB], sP2[WPB], sP3[WPB], sP4[WPB];
    __shared__ int   sEH, sEC, sEU, sEL;
    __shared__ float sEM, sA;
    __shared__ float sth2[MAXF];
    if (tid < MAXF) sth2[tid] = gth2[tid];

    // ---------------- W1: load inputs ----------------
    float upv[CH], uv[CH], labv[CH], av[CH];
    #pragma unroll
    for (int q = 0; q < CH / 4; ++q) {
        float4 t;
        t = ((const float4*)(gup + base))[q];
        upv[4*q]=t.x; upv[4*q+1]=t.y; upv[4*q+2]=t.z; upv[4*q+3]=t.w;
        t = ((const float4*)(gu + base))[q];
        uv[4*q]=t.x; uv[4*q+1]=t.y; uv[4*q+2]=t.z; uv[4*q+3]=t.w;
        t = ((const float4*)(glab + base))[q];
        labv[4*q]=t.x; labv[4*q+1]=t.y; labv[4*q+2]=t.z; labv[4*q+3]=t.w;
        t = ((const float4*)(ga + base))[q];
        av[4*q]=t.x; av[4*q+1]=t.y; av[4*q+2]=t.z; av[4*q+3]=t.w;
    }
    // prev-element: from lane-1's last vector element; lane 0 loads from global
    float up_prev0 = __shfl_up(upv[CH-1], 1, 64);
    float u_prev0  = __shfl_up(uv[CH-1], 1, 64);
    if (lane == 0) {
        up_prev0 = base ? gup[base - 1] : 0.f;
        u_prev0  = base ? gu[base - 1]  : 0.f;
    }

    // events thread aggregate (invariant: c==0 while h==0)
    int th = 0, tc = 0, tlu = -1, tll = -1; float tm = 0.f;
    {
        float pu = up_prev0, puu = u_prev0;
        #pragma unroll
        for (int j = 0; j < CH; ++j) {
            float x = upv[j];
            bool cross = (pu < 0.5f) && (x >= 0.5f);
            if (cross) { th = 1; tc = base + j; tm = x; } else tm = fmaxf(tm, x);
            if (puu == 0.f && uv[j] == 1.f) tlu = base + j;
            if (labv[j] >= 0.5f && x >= 0.5f) tll = base + j;
            pu = x; puu = uv[j];
        }
    }
    // wave inclusive scan (events monoid)
    int ih = th, ic = tc, iu = tlu, il = tll; float im = tm;
    #pragma unroll
    for (int off = 1; off < 64; off <<= 1) {
        int   ph = __shfl_up(ih, off, 64);
        float pm = __shfl_up(im, off, 64);
        int   pc = __shfl_up(ic, off, 64);
        int   pu = __shfl_up(iu, off, 64);
        int   pl = __shfl_up(il, off, 64);
        if (lane >= off) {
            if (!ih) { im = fmaxf(pm, im); ic = pc; ih = ph; }
            if (iu < 0) iu = pu;
            if (il < 0) il = pl;
        }
    }
    int eh = __shfl_up(ih, 1, 64), ec = __shfl_up(ic, 1, 64);
    int eu2 = __shfl_up(iu, 1, 64), el2 = __shfl_up(il, 1, 64);
    float em = __shfl_up(im, 1, 64);
    if (lane == 0) { eh = 0; em = 0.f; ec = 0; eu2 = -1; el2 = -1; }
    if (lane == 63) { sWH[wid]=ih; sWM[wid]=im; sWC[wid]=ic; sWU[wid]=iu; sWL[wid]=il; }
    __syncthreads();
    int wh = 0, wc2 = 0, wu = -1, wl = -1; float wm = 0.f;
    for (int w = 0; w < wid; ++w) {
        int hh = sWH[w]; float mm = sWM[w];
        if (hh) { wh = 1; wm = mm; wc2 = sWC[w]; } else wm = fmaxf(wm, mm);
        int su = sWU[w]; if (su >= 0) wu = su;
        int sl = sWL[w]; if (sl >= 0) wl = sl;
    }
    int xh, xc; float xm;
    if (eh) { xh = 1; xm = em; xc = ec; } else { xh = wh; xm = fmaxf(wm, em); xc = wc2; }
    const int xlu = (eu2 >= 0) ? eu2 : wu;
    const int xll = (el2 >= 0) ? el2 : wl;
    if (tid == THREADS - 1) {
        int BH, BC; float BM;
        if (ih) { BH = 1; BM = im; BC = ic; } else { BH = wh; BM = fmaxf(wm, im); BC = wc2; }
        int BU = (iu >= 0) ? iu : wu, BL = (il >= 0) ? il : wl;
        AST(&evH[b], BH); AST(&evM[b], BM); AST(&evC[b], BC);
        AST(&evU[b], BU); AST(&evL[b], BL);
    }
    gb_wait(ctr + 0);

    // ---------------- R1: grid events EXCLUSIVE scan (wave 0, 1 slot/lane) ----------------
    if (tid < 64) {
        int h = ALD(&evH[tid]); float m = ALD(&evM[tid]);
        int cc = ALD(&evC[tid]); int uu = ALD(&evU[tid]); int ll = ALD(&evL[tid]);
        #pragma unroll
        for (int off = 1; off < 64; off <<= 1) {
            int   ph = __shfl_up(h,  off, 64);
            float pm = __shfl_up(m,  off, 64);
            int   pc = __shfl_up(cc, off, 64);
            int   pu = __shfl_up(uu, off, 64);
            int   pl = __shfl_up(ll, off, 64);
            if (lane >= off) {
                if (!h) { m = fmaxf(pm, m); cc = pc; h = ph; }
                if (uu < 0) uu = pu;
                if (ll < 0) ll = pl;
            }
        }
        int geh = __shfl_up(h, 1, 64),  gec = __shfl_up(cc, 1, 64);
        int geu = __shfl_up(uu, 1, 64), gel = __shfl_up(ll, 1, 64);
        float gem = __shfl_up(m, 1, 64);
        if (lane == 0) { geh = 0; gem = 0.f; gec = 0; geu = -1; gel = -1; }
        if (tid == b) { sEH = geh; sEM = gem; sEC = gec; sEU = geu; sEL = gel; }
    }
    __syncthreads();
    const float m_in  = xh ? xm : fmaxf(sEM, xm);
    const int   c_in  = xh ? xc : sEC;                   // c==0 when h==0 invariant
    const int   ts_in = (xlu >= 0) ? xlu : ((sEU >= 0) ? sEU : 0);
    const int   lf_in = (xll >= 0) ? xll : ((sEL >= 0) ? sEL : 0);

    // ---------------- W2: up_hat + alpha affine ----------------
    float uphv[CH];
    float MA = 1.f, BA = 0.f;
    {
        float m = m_in, pu = up_prev0;
        #pragma unroll
        for (int j = 0; j < CH; ++j) {
            float x = upv[j];
            bool cross = (pu < 0.5f) && (x >= 0.5f);
            m = cross ? x : fmaxf(m, x);
            float uph = (x >= 0.5f) ? m : x;
            uphv[j] = uph;
            BA = uph * BA + (1.f - uph) * av[j];
            MA = uph * MA;
            pu = x;
        }
        #pragma unroll
        for (int q = 0; q < CH / 4; ++q)
            ((float4*)(out + 2*T + base))[q] =
                make_float4(uphv[4*q], uphv[4*q+1], uphv[4*q+2], uphv[4*q+3]);
    }
    float iM = MA, iB = BA;
    #pragma unroll
    for (int off = 1; off < 64; off <<= 1) {
        float pM = __shfl_up(iM, off, 64), pB = __shfl_up(iB, off, 64);
        if (lane >= off) { iB = iM * pB + iB; iM = iM * pM; }
    }
    float eM = __shfl_up(iM, 1, 64), eB = __shfl_up(iB, 1, 64);
    if (lane == 0) { eM = 1.f; eB = 0.f; }
    if (lane == 63) { sWM[wid] = iM; sWB[wid] = iB; }
    __syncthreads();
    float wM = 1.f, wB = 0.f;
    for (int w = 0; w < wid; ++w) { float cM = sWM[w], cB = sWB[w]; wB = cM * wB + cB; wM = cM * wM; }
    const float txM = eM * wM, txB = eM * wB + eB;
    if (tid == THREADS - 1) { AST(&aMg[b], iM * wM); AST(&aBg[b], iM * wB + iB); }
    gb_wait(ctr + 1);

    // ---------------- R2: grid alpha EXCLUSIVE scan ----------------
    if (tid < 64) {
        float M2 = ALD(&aMg[tid]), B2 = ALD(&aBg[tid]);
        #pragma unroll
        for (int off = 1; off < 64; off <<= 1) {
            float pM = __shfl_up(M2, off, 64), pB = __shfl_up(B2, off, 64);
            if (lane >= off) { B2 = M2 * pB + B2; M2 = M2 * pM; }
        }
        float xB = __shfl_up(B2, 1, 64);
        if (lane == 0) xB = 0.f;
        if (tid == b) sA = xB;
    }
    __syncthreads();
    const float alpha_in = txM * sA + txB;

    // ---------------- W3: alpha + y affine ----------------
    float alv[CH];
    float MY = 1.f, BY = 0.f;
    {
        float al = alpha_in; int c = c_in; float pu = up_prev0;
        #pragma unroll
        for (int j = 0; j < CH; ++j) {
            int t = base + j;
            float x = upv[j];
            bool cross = (pu < 0.5f) && (x >= 0.5f);
            if (cross) c = t;
            float uph = uphv[j];
            al = uph * al + (1.f - uph) * av[j];
            alv[j] = al;
            bool end    = (pu >= 0.5f) && (x < 0.5f);
            bool freeze = (x >= 0.5f) && (c > 0) && ((t - c) > MAXF);
            float A, B;
            if (end)         { A = 0.f;      B = 0.f; }
            else if (freeze) { A = 1.f;      B = 0.f; }
            else             { A = 1.f - al; B = al * uph; }
            BY = A * BY + B;
            MY = A * MY;
            pu = x;
        }
        #pragma unroll
        for (int q = 0; q < CH / 4; ++q)
            ((float4*)(out + T + base))[q] =
                make_float4(alv[4*q], alv[4*q+1], alv[4*q+2], alv[4*q+3]);
    }
    float jM = MY, jB = BY;
    #pragma unroll
    for (int off = 1; off < 64; off <<= 1) {
        float pM = __shfl_up(jM, off, 64), pB = __shfl_up(jB, off, 64);
        if (lane >= off) { jB = jM * pB + jB; jM = jM * pM; }
    }
    float fM = __shfl_up(jM, 1, 64), fB = __shfl_up(jB, 1, 64);
    if (lane == 0) { fM = 1.f; fB = 0.f; }
    if (lane == 63) { sWM[wid] = jM; sWB[wid] = jB; }
    __syncthreads();
    float vM = 1.f, vB = 0.f;
    for (int w = 0; w < wid; ++w) { float cM = sWM[w], cB = sWB[w]; vB = cM * vB + cB; vM = cM * vM; }
    const float tyM = fM * vM, tyB = fM * vB + fB;
    if (tid == THREADS - 1) { AST(&yMg[b], jM * vM); AST(&yBg[b], jM * vB + jB); }
    gb_wait(ctr + 2);

    // ---------------- R3: grid y EXCLUSIVE scan ----------------
    if (tid < 64) {
        float M2 = ALD(&yMg[tid]), B2 = ALD(&yBg[tid]);
        #pragma unroll
        for (int off = 1; off < 64; off <<= 1) {
            float pM = __shfl_up(M2, off, 64), pB = __shfl_up(B2, off, 64);
            if (lane >= off) { B2 = M2 * pB + B2; M2 = M2 * pM; }
        }
        float xB = __shfl_up(B2, 1, 64);
        if (lane == 0) xB = 0.f;
        if (tid == b) sA = xB;
    }
    __syncthreads();
    const float y_in = tyM * sA + tyB;

    // ---------------- W4: y + loss + lc setter (invariant: lc==0 while seen==0) ----------------
    float loss = 0.f, cnt = 0.f;
    int seen = 0; float lc = 0.f;
    int hasPend = 0, pendGood = 0, pendY05 = 0; float pendE = 0.f;
    {
        float yv[CH];
        float y = y_in; int c = c_in, ts = ts_in, lf = lf_in;
        float pu = up_prev0, puu = u_prev0;
        #pragma unroll
        for (int j = 0; j < CH; ++j) {
            int t = base + j;
            float x = upv[j];
            bool cross = (pu < 0.5f) && (x >= 0.5f);
            if (cross) c = t;
            float uph = uphv[j];
            float al  = alv[j];
            bool end    = (pu >= 0.5f) && (x < 0.5f);
            bool freeze = (x >= 0.5f) && (c > 0) && ((t - c) > MAXF);
            float yr = al * uph + (1.f - al) * y;
            float yt = end ? 0.f : (freeze ? y : yr);
            yv[j] = yt;
            if (puu == 0.f && uv[j] == 1.f) ts = t;
            bool islab = labv[j] >= 0.5f;
            if (islab && x >= 0.5f) lf = t;
            if (end) {
                int dur = lf - ts + 1;
                bool good = (dur >= 3) && (dur <= 40);
                if (islab) {
                    // lc_used = -1 -> no loss case fires
                } else if (seen) {
                    float lcu = lc;
                    if (lcu != -1.f && lcu != 0.f && good) { loss += lcu; cnt += 1.f; }
                    if (lcu == 0.f && y >= 0.5f) {
                        int d = t - c; int idx = (d < MAXF) ? d : (MAXF - 1); idx = idx < 0 ? 0 : idx;
                        float df = y - sth2[idx]; loss += df * df; cnt += 1.f;
                    }
                } else {
                    hasPend = 1; pendGood = good ? 1 : 0; pendY05 = (y >= 0.5f) ? 1 : 0;
                    int d = t - c; int idx = (d < MAXF) ? d : (MAXF - 1); idx = idx < 0 ? 0 : idx;
                    float df = y - sth2[idx]; pendE = df * df;
                }
                lc = 0.f; seen = 1;
            } else if (islab) {
                lc = (x < 0.5f) ? -1.f : (yt - labv[j]) * (yt - labv[j]);
                seen = 1;
            }
            y = yt; pu = x; puu = uv[j];
        }
        #pragma unroll
        for (int q = 0; q < CH / 4; ++q)
            ((float4*)(out + base))[q] =
                make_float4(yv[4*q], yv[4*q+1], yv[4*q+2], yv[4*q+3]);
    }
    // block lc scan
    int is_ = seen; float iv = lc;
    #pragma unroll
    for (int off = 1; off < 64; off <<= 1) {
        int ph = __shfl_up(is_, off, 64); float pv = __shfl_up(iv, off, 64);
        if (lane >= off && !is_) { is_ = ph; iv = pv; }
    }
    int es = __shfl_up(is_, 1, 64); float evx = __shfl_up(iv, 1, 64);
    if (lane == 0) { es = 0; evx = 0.f; }
    if (lane == 63) { sWH[wid] = is_; sWB[wid] = iv; }
    __syncthreads();
    int ws = 0; float wv = 0.f;
    for (int w = 0; w < wid; ++w) { if (sWH[w]) { ws = 1; wv = sWB[w]; } }
    const int   tlh = es ? 1   : ws;
    const float tlv = es ? evx : wv;
    if (tid == THREADS - 1) {
        int BS = is_ ? 1 : ws; float BV = is_ ? iv : wv;
        AST(&lcHg[b], BS); AST(&lcVg[b], BV);
    }
    // resolve pendings (local if setter in block prefix; else closed-form publish)
    float PGl = 0.f, PEl = 0.f, PYl = 0.f;
    if (hasPend) {
        if (tlh) {
            float lcv = tlv;
            if (lcv == 0.f) { if (pendY05) { loss += pendE; cnt += 1.f; } }
            else if (lcv != -1.f) { if (pendGood) { loss += lcv; cnt += 1.f; } }
        } else {
            PGl = pendGood ? 1.f : 0.f;
            PYl = pendY05 ? 1.f : 0.f;
            PEl = pendY05 ? pendE : 0.f;
        }
    }
    float rL = loss, rC = cnt, rG = PGl, rE = PEl, rY = PYl;
    #pragma unroll
    for (int off = 32; off; off >>= 1) {
        rL += __shfl_xor(rL, off, 64); rC += __shfl_xor(rC, off, 64);
        rG += __shfl_xor(rG, off, 64); rE += __shfl_xor(rE, off, 64);
        rY += __shfl_xor(rY, off, 64);
    }
    if (lane == 0) { sP0[wid] = rL; sP1[wid] = rC; sP2[wid] = rG; sP3[wid] = rE; sP4[wid] = rY; }
    __syncthreads();
    if (tid == 0) {
        float L = 0.f, C = 0.f, G = 0.f, E = 0.f, Y = 0.f;
        #pragma unroll
        for (int w = 0; w < WPB; ++w) { L += sP0[w]; C += sP1[w]; G += sP2[w]; E += sP3[w]; Y += sP4[w]; }
        AST(&loK[b], L); AST(&cnK[b], C); AST(&pGg[b], G); AST(&pEg[b], E); AST(&pYg[b], Y);
    }

    if (b == 0) {
        gb_wait(ctr + 3);
        if (tid < 64) {
            int h = ALD(&lcHg[tid]); float v = ALD(&lcVg[tid]);
            #pragma unroll
            for (int off = 1; off < 64; off <<= 1) {
                int ph = __shfl_up(h, off, 64); float pv = __shfl_up(v, off, 64);
                if (lane >= off && !h) { h = ph; v = pv; }
            }
            float xv = __shfl_up(v, 1, 64);
            if (lane == 0) xv = 0.f;
            const float lcb = xv;                   // v==0 while h==0 invariant
            float Lb = ALD(&loK[tid]), Cb = ALD(&cnK[tid]);
            float G = ALD(&pGg[tid]), E = ALD(&pEg[tid]), Y = ALD(&pYg[tid]);
            if (lcb == 0.f) { Lb += E; Cb += Y; }
            else if (lcb != -1.f) { Lb += lcb * G; Cb += G; }
            #pragma unroll
            for (int off = 32; off; off >>= 1) {
                Lb += __shfl_xor(Lb, off, 64); Cb += __shfl_xor(Cb, off, 64);
            }
            if (tid == 0) { out[3 * T] = Lb; out[3 * T + 1] = Cb; }
        }
    } else {
        gb_arrive(ctr + 3);
    }
}

extern "C" void kernel_launch(void* const* d_in, const int* in_sizes, int n_in,
                              void* d_out, int out_size, void* d_ws, size_t ws_size,
                              hipStream_t stream) {
    const float* a   = (const float*)d_in[0];
    const float* u   = (const float*)d_in[1];
    const float* up  = (const float*)d_in[2];
    const float* lab = (const float*)d_in[3];
    const float* th2 = (const float*)d_in[4];
    float* out = (float*)d_out;
    const int T = in_sizes[0];

    unsigned* ctr = (unsigned*)d_ws;
    float* W = (float*)d_ws + 32;   // 128B offset for aggregate arrays

    (void)hipMemsetAsync(d_ws, 0, 32 * sizeof(unsigned), stream);
    tg_fused<<<NBLK, THREADS, 0, stream>>>(a, u, up, lab, th2, out, T, ctr, W);
}